// Round 16
// baseline (454.315 us; speedup 1.0000x reference)
//
#include <hip/hip_runtime.h>

#define S_ 1024
#define D_ 512
#define DCH 8       // denom chunk length (f64 pipeline)
#define NDCH 128    // denom chunks per batch
#define CT 32       // GEMM-scan chunk length
#define NCT 32      // GEMM-scan chunks per batch

using bf16x8 = __attribute__((ext_vector_type(8))) short;
using f32x4  = __attribute__((ext_vector_type(4))) float;

__device__ __forceinline__ unsigned short f2bf(float x) {
    unsigned int u = __float_as_uint(x);
    u = (u + 0x7FFFu + ((u >> 16) & 1u)) >> 16;
    return (unsigned short)u;
}
__device__ __forceinline__ float bf2f(unsigned short s) {
    return __uint_as_float(((unsigned int)s) << 16);
}
__device__ __forceinline__ bf16x8 cvt8(const float* __restrict__ p) {
    float4 a = *(const float4*)p;
    float4 b = *(const float4*)(p + 4);
    bf16x8 r;
    r[0] = (short)f2bf(a.x); r[1] = (short)f2bf(a.y);
    r[2] = (short)f2bf(a.z); r[3] = (short)f2bf(a.w);
    r[4] = (short)f2bf(b.x); r[5] = (short)f2bf(b.y);
    r[6] = (short)f2bf(b.z); r[7] = (short)f2bf(b.w);
    return r;
}
__device__ __forceinline__ void gload_lds16(const void* g, void* l) {
    __builtin_amdgcn_global_load_lds(
        (const __attribute__((address_space(1))) void*)g,
        (__attribute__((address_space(3))) void*)l, 16, 0, 0);
}

// Tiled-swizzled bf16 operand layout (cvt_a / prep_w / gemm_mfma):
// tile = (rowblk = row>>7, kblk = k>>5), 4096 elems (8 KB).
// within tile: elem = (row&127)*32 + (((k>>3)&3 ^ ((row>>1)&3))<<3) + (k&7)
// perm = (row>>1)&3 -> quarter-wave spreads over all 4 even/odd 4-bank
// groups 2x each = conflict-free ds_read_b128 (verified R15: conflicts = 0).
// 64-row half-tiles stay consistent: 64-aligned bases shift perm by 0.

// ---------------------------------------------------------------------------
// prep_w: weights -> bf16 hi/lo in tiled-swizzled [n][k] layout.
// ---------------------------------------------------------------------------
__global__ __launch_bounds__(256)
void prep_w(const float* __restrict__ W_in, const float* __restrict__ W_ig,
            const float* __restrict__ W_fg, const float* __restrict__ W_og,
            const float* __restrict__ W_out,
            unsigned short* __restrict__ Wh, unsigned short* __restrict__ Wl)
{
    const int n    = blockIdx.x * 256 + threadIdx.x;   // 0..3583
    const int kblk = blockIdx.y;                        // 0..15

    const float* src; int ldw, col;
    if (n < 1536)       { src = W_in;  ldw = 2048; col = n; }
    else if (n < 3072)  {
        const int g = (n - 1536) >> 9;
        src = (g == 0) ? W_ig : (g == 1) ? W_fg : W_og;
        ldw = 512; col = (n - 1536) & 511;
    } else              { src = W_out; ldw = 512; col = n - 3072; }

    unsigned int hw[16], lw[16];
#pragma unroll
    for (int j = 0; j < 32; j += 2) {
        const int k = kblk * 32 + j;
        float f0 = src[(size_t)k * ldw + col];
        float f1 = src[(size_t)(k + 1) * ldw + col];
        unsigned short h0 = f2bf(f0), h1 = f2bf(f1);
        unsigned short l0 = f2bf(f0 - bf2f(h0)), l1 = f2bf(f1 - bf2f(h1));
        hw[j >> 1] = (unsigned int)h0 | ((unsigned int)h1 << 16);
        lw[j >> 1] = (unsigned int)l0 | ((unsigned int)l1 << 16);
    }
    const size_t base = ((size_t)(n >> 7) * 16 + kblk) * 4096 + ((n & 127) << 5);
    const int perm = (n >> 1) & 3;
#pragma unroll
    for (int g = 0; g < 4; ++g) {
        const size_t dst = base + (size_t)((g ^ perm) << 3);
        *(uint4*)(Wh + dst) = make_uint4(hw[g*4], hw[g*4+1], hw[g*4+2], hw[g*4+3]);
        *(uint4*)(Wl + dst) = make_uint4(lw[g*4], lw[g*4+1], lw[g*4+2], lw[g*4+3]);
    }
}

// ---------------------------------------------------------------------------
// cvt_a: A f32 (row stride lda) -> bf16 hi/lo tiled-swizzled.
// ---------------------------------------------------------------------------
__global__ __launch_bounds__(256)
void cvt_a(const float* __restrict__ A, int lda,
           unsigned short* __restrict__ Ah, unsigned short* __restrict__ Al)
{
    const int m    = blockIdx.x * 256 + threadIdx.x;   // 0..8191
    const int kblk = blockIdx.y;                        // 0..15
    const float* p = A + (size_t)m * lda + kblk * 32;
    const size_t base = ((size_t)(m >> 7) * 16 + kblk) * 4096 + ((m & 127) << 5);
    const int perm = (m >> 1) & 3;
#pragma unroll
    for (int g = 0; g < 4; ++g) {
        float4 a = *(const float4*)(p + g * 8);
        float4 b = *(const float4*)(p + g * 8 + 4);
        float f[8] = {a.x, a.y, a.z, a.w, b.x, b.y, b.z, b.w};
        unsigned int hw[4], lw[4];
#pragma unroll
        for (int j = 0; j < 4; ++j) {
            unsigned short h0 = f2bf(f[2*j]), h1 = f2bf(f[2*j+1]);
            unsigned short l0 = f2bf(f[2*j] - bf2f(h0));
            unsigned short l1 = f2bf(f[2*j+1] - bf2f(h1));
            hw[j] = (unsigned int)h0 | ((unsigned int)h1 << 16);
            lw[j] = (unsigned int)l0 | ((unsigned int)l1 << 16);
        }
        const size_t dst = base + (size_t)((g ^ perm) << 3);
        *(uint4*)(Ah + dst) = make_uint4(hw[0], hw[1], hw[2], hw[3]);
        *(uint4*)(Al + dst) = make_uint4(lw[0], lw[1], lw[2], lw[3]);
    }
}

// ---------------------------------------------------------------------------
// gemm_mfma<MODE>: bfx3 MFMA GEMM, m97 structure at its proper operating
// point: 2-wave blocks (128 thr), BM=128 x BN=64, BK=32, 48 KB LDS double-
// buffered -> 3 independent blocks/CU whose staggered barriers overlap each
// other's vmcnt drains (m114).  Wave = 64x64 tile (unchanged fragments).
// MODE 0: nbase 0,    nbt 24, ldc 1536, tanh n<1024
// MODE 1: nbase 1536, nbt 24, ldc 1536, sigmoid, n<512 fused *k
// MODE 2: nbase 3072, nbt 8,  ldc 512,  none
// ---------------------------------------------------------------------------
template<int MODE>
__global__ __launch_bounds__(128)
void gemm_mfma(const unsigned short* __restrict__ Ah,
               const unsigned short* __restrict__ Al,
               const unsigned short* __restrict__ Wh,
               const unsigned short* __restrict__ Wl,
               const float* __restrict__ qkv,
               const float* __restrict__ bb0, const float* __restrict__ bb1,
               const float* __restrict__ bb2,
               float* __restrict__ Co, int ldc)
{
    __shared__ unsigned short ldsA[2][2][4096];   // [buf][hi/lo][128x32 tile]
    __shared__ unsigned short ldsB[2][2][2048];   // [buf][hi/lo][64x32 half]

    const int tid  = threadIdx.x;
    const int lane = tid & 63;
    const int wv   = tid >> 6;                    // 0..1
    const int nbt  = (MODE == 2) ? 8 : 24;
    const int cpx  = gridDim.x >> 3;              // grid % 8 == 0
    const int swz  = (blockIdx.x & 7) * cpx + (blockIdx.x >> 3);
    const int n0blk = swz % nbt;
    const int m0blk = swz / nbt;
    const int l15  = lane & 15;
    const int kg   = lane >> 4;
    const int nbase = (MODE == 0) ? 0 : (MODE == 1) ? 1536 : 3072;

    const size_t abase = (size_t)m0blk * 16 * 4096;
    const int    nabs  = nbase + n0blk * 64;
    const size_t wtile = (size_t)(nabs >> 7) * 16;
    const int    whalf = (nabs & 64) << 5;        // 0 or 2048 elems

    f32x4 acc[4][4];
#pragma unroll
    for (int mf = 0; mf < 4; ++mf)
#pragma unroll
        for (int nf = 0; nf < 4; ++nf) acc[mf][nf] = (f32x4){0.f, 0.f, 0.f, 0.f};

    auto STAGE = [&](int buf, int kblk) {
        const unsigned short* sa[2] = {
            Ah + abase + (size_t)kblk * 4096, Al + abase + (size_t)kblk * 4096};
        const unsigned short* sw[2] = {
            Wh + (wtile + kblk) * 4096 + whalf, Wl + (wtile + kblk) * 4096 + whalf};
#pragma unroll
        for (int p = 0; p < 2; ++p) {
#pragma unroll
            for (int h = 0; h < 4; ++h)
                gload_lds16(sa[p] + h * 1024 + (size_t)tid * 8,
                            &ldsA[buf][p][h * 1024 + wv * 512]);
#pragma unroll
            for (int h = 0; h < 2; ++h)
                gload_lds16(sw[p] + h * 1024 + (size_t)tid * 8,
                            &ldsB[buf][p][h * 1024 + wv * 512]);
        }
    };

    STAGE(0, 0);
    __syncthreads();

    int cur = 0;
    for (int ks = 0; ks < 16; ++ks) {
        if (ks + 1 < 16) STAGE(cur ^ 1, ks + 1);

        bf16x8 ah[4], al[4], bh[4], bl[4];
#pragma unroll
        for (int i = 0; i < 4; ++i) {
            const int ra = wv * 64 + i * 16 + l15;           // 0..127
            const int oa = ra * 32 + ((kg ^ ((ra >> 1) & 3)) << 3);
            ah[i] = *(const bf16x8*)&ldsA[cur][0][oa];
            al[i] = *(const bf16x8*)&ldsA[cur][1][oa];
            const int rw = i * 16 + l15;                     // 0..63
            const int ow = rw * 32 + ((kg ^ ((rw >> 1) & 3)) << 3);
            bh[i] = *(const bf16x8*)&ldsB[cur][0][ow];
            bl[i] = *(const bf16x8*)&ldsB[cur][1][ow];
        }
#pragma unroll
        for (int nf = 0; nf < 4; ++nf)
#pragma unroll
            for (int mf = 0; mf < 4; ++mf) {
                acc[mf][nf] = __builtin_amdgcn_mfma_f32_16x16x32_bf16(ah[mf], bh[nf], acc[mf][nf], 0, 0, 0);
                acc[mf][nf] = __builtin_amdgcn_mfma_f32_16x16x32_bf16(al[mf], bh[nf], acc[mf][nf], 0, 0, 0);
                acc[mf][nf] = __builtin_amdgcn_mfma_f32_16x16x32_bf16(ah[mf], bl[nf], acc[mf][nf], 0, 0, 0);
            }
        __syncthreads();
        cur ^= 1;
    }

    // epilogue: D col = l15, row = kg*4 + vi
    const int m0 = m0blk * 128 + wv * 64;
    const int n0 = n0blk * 64;
#pragma unroll
    for (int mf = 0; mf < 4; ++mf) {
#pragma unroll
        for (int vi = 0; vi < 4; ++vi) {
            const int m = m0 + mf * 16 + kg * 4 + vi;
            float* crow = Co + (size_t)m * ldc;
#pragma unroll
            for (int nf = 0; nf < 4; ++nf) {
                const int n = n0 + nf * 16 + l15;
                float bias;
                if (MODE == 1) {
                    const int g = n >> 9;
                    bias = (g == 0 ? bb0 : g == 1 ? bb1 : bb2)[n & 511];
                } else {
                    bias = bb0[n];
                }
                float v = acc[mf][nf][vi] + bias;
                if (MODE == 0) {
                    if (n < 1024) v = tanhf(v);
                } else if (MODE == 1) {
                    v = 1.0f / (1.0f + expf(-v));
                    if (n < 512) v *= qkv[(size_t)m * 1536 + 512 + n];
                }
                crow[n] = v;
            }
        }
    }
}

// ---------------------------------------------------------------------------
// f64 denominator pipeline (unchanged, DCH=8)
// ---------------------------------------------------------------------------
__global__ __launch_bounds__(512)
void nscan_local(const float* __restrict__ GG,
                 double* __restrict__ nend, double* __restrict__ Dend)
{
    const int b = blockIdx.x >> 7;
    const int c = blockIdx.x & 127;
    const int d = threadIdx.x;
    const float* gb = GG + (size_t)b * S_ * 1536 + (size_t)c * DCH * 1536;
    double n = 0.0, P = 1.0;
    for (int u = 0; u < DCH; ++u) {
        const float* row = gb + (size_t)u * 1536;
        const double ik = (double)row[d];
        const double f  = (double)row[512 + d];
        n = fma(f, n, ik);
        P *= f;
    }
    nend[(size_t)blockIdx.x * 512 + d] = n;
    Dend[(size_t)blockIdx.x * 512 + d] = P;
}

__global__ __launch_bounds__(512)
void nscan_stitch(const double* __restrict__ nend, const double* __restrict__ Dend,
                  double* __restrict__ n0a, float* __restrict__ nfO)
{
    const int b = blockIdx.x;
    const int d = threadIdx.x;
    double n0 = 0.0;
    for (int c = 0; c < NDCH; ++c) {
        const size_t idx = ((size_t)(b * NDCH + c)) * 512 + d;
        n0a[idx] = n0;
        n0 = fma(Dend[idx], n0, nend[idx]);
    }
    nfO[(size_t)b * 512 + d] = (float)n0;
}

__global__ __launch_bounds__(256)
void denom_kernel(const float* __restrict__ QKV, const float* __restrict__ GG,
                  const double* __restrict__ n0a, float* __restrict__ invd)
{
    const int lane = threadIdx.x & 63;
    const int widx = blockIdx.x * 4 + (threadIdx.x >> 6);
    const int b    = widx >> 7;
    const int c    = widx & 127;
    const int d0   = 4 * lane;

    const float* qb = QKV + (size_t)b * S_ * 1536 + (size_t)c * DCH * 1536;
    const float* gb = GG  + (size_t)b * S_ * 1536 + (size_t)c * DCH * 1536;
    const double* sp = n0a + (size_t)widx * 512;

    double n[2][4];
#pragma unroll
    for (int r = 0; r < 2; ++r) {
        double2 a = *(const double2*)(sp + d0 + 256 * r);
        double2 bb = *(const double2*)(sp + d0 + 256 * r + 2);
        n[r][0] = a.x; n[r][1] = a.y; n[r][2] = bb.x; n[r][3] = bb.y;
    }

    for (int t0 = 0; t0 < DCH; t0 += 4) {
        double dq[4];
#pragma unroll
        for (int i = 0; i < 4; ++i) {
            const float* qr = qb + (size_t)(t0 + i) * 1536;
            const float* gr = gb + (size_t)(t0 + i) * 1536;
            double acc = 0.0;
#pragma unroll
            for (int r = 0; r < 2; ++r) {
                float4 qf = *(const float4*)(qr + d0 + 256 * r);
                float4 kf = *(const float4*)(gr + d0 + 256 * r);
                float4 ff = *(const float4*)(gr + 512 + d0 + 256 * r);
                const float* qp = (const float*)&qf;
                const float* kp = (const float*)&kf;
                const float* fp = (const float*)&ff;
#pragma unroll
                for (int j = 0; j < 4; ++j) {
                    n[r][j] = fma((double)fp[j], n[r][j], (double)kp[j]);
                    acc = fma((double)qp[j], n[r][j], acc);
                }
            }
            dq[i] = acc;
        }
        double u0 = dq[0] + __shfl_xor(dq[0], 32);
        double u1 = dq[1] + __shfl_xor(dq[1], 32);
        double u2 = dq[2] + __shfl_xor(dq[2], 32);
        double u3 = dq[3] + __shfl_xor(dq[3], 32);
        double w0 = (lane & 32) ? u2 : u0;
        double w1 = (lane & 32) ? u3 : u1;
        w0 += __shfl_xor(w0, 16);
        w1 += __shfl_xor(w1, 16);
        double y = (lane & 16) ? w1 : w0;
        y += __shfl_xor(y, 8); y += __shfl_xor(y, 4);
        y += __shfl_xor(y, 2); y += __shfl_xor(y, 1);
        if ((lane & 15) == 0) {
            const int g = lane >> 4;
            const double den = (y > 1e-6) ? y : 1e-6;
            invd[(size_t)b * S_ + c * DCH + t0 + g] = (float)(1.0 / den);
        }
    }
}

// ---------------------------------------------------------------------------
// chunk_prep (unchanged)
// ---------------------------------------------------------------------------
__global__ __launch_bounds__(512)
void chunk_prep(float* __restrict__ qkv, float* __restrict__ gg)
{
    const int b = blockIdx.x >> 5;
    const int c = blockIdx.x & 31;
    const int d = threadIdx.x;
    float* qr = qkv + ((size_t)(b * S_ + c * CT)) * 1536 + d;
    float* gr = gg  + ((size_t)(b * S_ + c * CT)) * 1536 + d;
    float* ft = gr + 512;
    float F = 1.f;
    for (int u = 0; u < CT; ++u) {
        const float q = qr[0], ik = gr[0], f = gr[512];
        F *= f;
        qr[0] = q * F;
        gr[0] = ik / F;
        qr += 1536; gr += 1536;
    }
    ft[0] = F;
}

// ---------------------------------------------------------------------------
// chunk_A (unchanged): H1 = tril(Qt Kt^T) V -> hsb
// ---------------------------------------------------------------------------
__global__ __launch_bounds__(256)
void chunk_A(const float* __restrict__ qkv, const float* __restrict__ gg,
             float* __restrict__ h1out)
{
    const int b   = blockIdx.x >> 5;
    const int c   = blockIdx.x & 31;
    const int tid = threadIdx.x;
    const int t   = tid & 31;
    const int g   = tid >> 5;

    __shared__ float sA[32][33];

    const size_t rb = (size_t)(b * S_ + c * CT);
    const float* qr = qkv + (rb + t) * 1536;
    const float* kb = gg + rb * 1536;

    {
        const int s0 = g * 4;
        const float* k0 = kb + (size_t)(s0 + 0) * 1536;
        const float* k1 = kb + (size_t)(s0 + 1) * 1536;
        const float* k2 = kb + (size_t)(s0 + 2) * 1536;
        const float* k3 = kb + (size_t)(s0 + 3) * 1536;
        float a0 = 0.f, a1 = 0.f, a2 = 0.f, a3 = 0.f;
        for (int d4 = 0; d4 < 512; d4 += 4) {
            float4 qv = *(const float4*)(qr + d4);
            float4 x0 = *(const float4*)(k0 + d4);
            float4 x1 = *(const float4*)(k1 + d4);
            float4 x2 = *(const float4*)(k2 + d4);
            float4 x3 = *(const float4*)(k3 + d4);
            a0 = fmaf(qv.x, x0.x, a0); a0 = fmaf(qv.y, x0.y, a0);
            a0 = fmaf(qv.z, x0.z, a0); a0 = fmaf(qv.w, x0.w, a0);
            a1 = fmaf(qv.x, x1.x, a1); a1 = fmaf(qv.y, x1.y, a1);
            a1 = fmaf(qv.z, x1.z, a1); a1 = fmaf(qv.w, x1.w, a1);
            a2 = fmaf(qv.x, x2.x, a2); a2 = fmaf(qv.y, x2.y, a2);
            a2 = fmaf(qv.z, x2.z, a2); a2 = fmaf(qv.w, x2.w, a2);
            a3 = fmaf(qv.x, x3.x, a3); a3 = fmaf(qv.y, x3.y, a3);
            a3 = fmaf(qv.z, x3.z, a3); a3 = fmaf(qv.w, x3.w, a3);
        }
        sA[t][s0 + 0] = (s0 + 0 <= t) ? a0 : 0.f;
        sA[t][s0 + 1] = (s0 + 1 <= t) ? a1 : 0.f;
        sA[t][s0 + 2] = (s0 + 2 <= t) ? a2 : 0.f;
        sA[t][s0 + 3] = (s0 + 3 <= t) ? a3 : 0.f;
    }
    __syncthreads();

    {
        const int e0 = g * 64;
        float4 h[16];
#pragma unroll
        for (int m = 0; m < 16; ++m) h[m] = make_float4(0.f, 0.f, 0.f, 0.f);
        const float* vb = qkv + rb * 1536 + 1024 + e0;
        for (int s = 0; s < CT; ++s) {
            const float a = sA[t][s];
            const float* vr = vb + (size_t)s * 1536;
#pragma unroll
            for (int m = 0; m < 16; ++m) {
                float4 vv = *(const float4*)(vr + m * 4);
                h[m].x = fmaf(a, vv.x, h[m].x);
                h[m].y = fmaf(a, vv.y, h[m].y);
                h[m].z = fmaf(a, vv.z, h[m].z);
                h[m].w = fmaf(a, vv.w, h[m].w);
            }
        }
        float* orow = h1out + (rb + t) * 512 + e0;
#pragma unroll
        for (int m = 0; m < 16; ++m) *(float4*)(orow + m * 4) = h[m];
    }
}

// ---------------------------------------------------------------------------
// chunk_cacc (unchanged): MFMA Cacc via LDS-transposed staging
// ---------------------------------------------------------------------------
__global__ __launch_bounds__(1024)
void chunk_cacc(const float* __restrict__ qkv, const float* __restrict__ gg,
                unsigned short* __restrict__ snap, int c0)
{
    __shared__ unsigned short vT[256][40];   // [e][u], padded pitch 40
    __shared__ unsigned short kT[512][40];   // [d][u]

    const int b    = blockIdx.x;
    const int lc   = blockIdx.y;
    const int eh   = blockIdx.z;
    const int c    = c0 + lc;
    const int tid  = threadIdx.x;
    const int lane = tid & 63;
    const int wv   = tid >> 6;          // 0..15
    const int l15  = lane & 15;
    const int kg   = lane >> 4;

    const size_t rb = (size_t)(b * S_ + c * CT);
    const size_t sb = ((size_t)lc * 8 + b) * 512;

    if (tid < 256) {
        const float* vp = qkv + rb * 1536 + 1024 + eh * 256 + tid;
        unsigned int pk[16];
#pragma unroll
        for (int u = 0; u < 32; u += 2) {
            float f0 = vp[(size_t)u * 1536];
            float f1 = vp[(size_t)(u + 1) * 1536];
            pk[u >> 1] = (unsigned int)f2bf(f0) | ((unsigned int)f2bf(f1) << 16);
        }
        uint4* dst = (uint4*)&vT[tid][0];
        dst[0] = make_uint4(pk[0],  pk[1],  pk[2],  pk[3]);
        dst[1] = make_uint4(pk[4],  pk[5],  pk[6],  pk[7]);
        dst[2] = make_uint4(pk[8],  pk[9],  pk[10], pk[11]);
        dst[3] = make_uint4(pk[12], pk[13], pk[14], pk[15]);
    } else if (tid < 768) {
        const int d = tid - 256;
        const float* kp = gg + rb * 1536 + d;
        unsigned int pk[16];
#pragma unroll
        for (int u = 0; u < 32; u += 2) {
            float f0 = kp[(size_t)u * 1536];
            float f1 = kp[(size_t)(u + 1) * 1536];
            pk[u >> 1] = (unsigned int)f2bf(f0) | ((unsigned int)f2bf(f1) << 16);
        }
        uint4* dst = (uint4*)&kT[d][0];
        dst[0] = make_uint4(pk[0],  pk[1],  pk[2],  pk[3]);
        dst[1] = make_uint4(pk[4],  pk[5],  pk[6],  pk[7]);
        dst[2] = make_uint4(pk[8],  pk[9],  pk[10], pk[11]);
        dst[3] = make_uint4(pk[12], pk[13], pk[14], pk[15]);
    }
    __syncthreads();

    const int ebase = (wv & 3) * 64;
    const int dbase = (wv >> 2) * 128;

    bf16x8 a[4];
#pragma unroll
    for (int me = 0; me < 4; ++me)
        a[me] = *(const bf16x8*)&vT[ebase + me * 16 + l15][kg * 8];

#pragma unroll
    for (int dp = 0; dp < 2; ++dp) {
        f32x4 acc[4][4];
#pragma unroll
        for (int me = 0; me < 4; ++me)
#pragma unroll
            for (int nd = 0; nd < 4; ++nd) acc[me][nd] = (f32x4){0.f, 0.f, 0.f, 0.f};

#pragma unroll
        for (int nd = 0; nd < 4; ++nd) {
            bf16x8 bfr = *(const bf16x8*)&kT[dbase + dp * 64 + nd * 16 + l15][kg * 8];
#pragma unroll
            for (int me = 0; me < 4; ++me)
                acc[me][nd] = __builtin_amdgcn_mfma_f32_16x16x32_bf16(a[me], bfr, acc[me][nd], 0, 0, 0);
        }

#pragma unroll
        for (int me = 0; me < 4; ++me)
#pragma unroll
            for (int vi = 0; vi < 4; ++vi) {
                const int e = eh * 256 + ebase + me * 16 + kg * 4 + vi;
                unsigned short* row = snap + (sb + e) * 512 + dbase + dp * 64;
#pragma unroll
                for (int nd = 0; nd < 4; ++nd)
                    row[nd * 16 + l15] = f2bf(acc[me][nd][vi]);
            }
    }
}

// ---------------------------------------------------------------------------
// chunk_cscan (unchanged): 32-step elementwise scan, snapshots in place
// ---------------------------------------------------------------------------
__global__ __launch_bounds__(256)
void chunk_cscan(const float* __restrict__ gg,
                 unsigned short* __restrict__ snap, float* __restrict__ Cst,
                 float* __restrict__ CfO, int c0, int nc)
{
    const int tid  = threadIdx.x;
    const int lane = tid & 63;
    const int wv   = tid >> 6;
    const int b    = blockIdx.x;
    const int eg   = blockIdx.y;
    const int dh   = blockIdx.z;
    const int ew   = eg * 16 + wv * 4;
    const int d0   = dh * 256 + 4 * lane;

    const float* gb = gg + (size_t)b * S_ * 1536;

    float C[4][4];
    if (c0 == 0) {
#pragma unroll
        for (int i = 0; i < 4; ++i)
#pragma unroll
            for (int j = 0; j < 4; ++j) C[i][j] = 0.f;
    } else {
#pragma unroll
        for (int j = 0; j < 4; ++j) {
            float4 cv = *(const float4*)&Cst[((size_t)b * 512 + d0 + j) * 512 + ew];
            C[0][j] = cv.x; C[1][j] = cv.y; C[2][j] = cv.z; C[3][j] = cv.w;
        }
    }

    ushort4 A0[4]; float4 F0;
    {
        const size_t sb = ((size_t)0 * 8 + b) * 512;
#pragma unroll
        for (int i = 0; i < 4; ++i)
            A0[i] = *(const ushort4*)(snap + (sb + ew + i) * 512 + d0);
        F0 = *(const float4*)(gb + (size_t)(c0 * CT) * 1536 + 512 + d0);
    }

    for (int lc = 0; lc < nc; ++lc) {
        ushort4 A1[4]; float4 F1;
        if (lc + 1 < nc) {
            const size_t sb = ((size_t)(lc + 1) * 8 + b) * 512;
#pragma unroll
            for (int i = 0; i < 4; ++i)
                A1[i] = *(const ushort4*)(snap + (sb + ew + i) * 512 + d0);
            F1 = *(const float4*)(gb + (size_t)((c0 + lc + 1) * CT) * 1536 + 512 + d0);
        }

        const int c = c0 + lc;
        if (c > 0) {
            const size_t sb = ((size_t)lc * 8 + b) * 512;
#pragma unroll
            for (int i = 0; i < 4; ++i) {
                uint2 pk;
                pk.x = (unsigned int)f2bf(C[i][0]) | ((unsigned int)f2bf(C[i][1]) << 16);
                pk.y = (unsigned int)f2bf(C[i][2]) | ((unsigned int)f2bf(C[i][3]) << 16);
                *(uint2*)(snap + (sb + ew + i) * 512 + d0) = pk;
            }
        }

        const float* fp = (const float*)&F0;
#pragma unroll
        for (int i = 0; i < 4; ++i) {
            C[i][0] = fp[0] * (C[i][0] + bf2f(A0[i].x));
            C[i][1] = fp[1] * (C[i][1] + bf2f(A0[i].y));
            C[i][2] = fp[2] * (C[i][2] + bf2f(A0[i].z));
            C[i][3] = fp[3] * (C[i][3] + bf2f(A0[i].w));
        }

        if (lc + 1 < nc) {
#pragma unroll
            for (int i = 0; i < 4; ++i) A0[i] = A1[i];
            F0 = F1;
        }
    }

    float* outp = (c0 + nc == NCT) ? CfO : Cst;
#pragma unroll
    for (int j = 0; j < 4; ++j)
        *(float4*)&outp[((size_t)b * 512 + d0 + j) * 512 + ew] =
            make_float4(C[0][j], C[1][j], C[2][j], C[3][j]);
}

// ---------------------------------------------------------------------------
// chunk_h2 (unchanged): H2 = Qt @ C0^T via mfma + fused combine epilogue
// ---------------------------------------------------------------------------
__global__ __launch_bounds__(256)
void chunk_h2(const float* __restrict__ qkv, const float* __restrict__ gg,
              const unsigned short* __restrict__ snap,
              const float* __restrict__ invd,
              float* __restrict__ hs, float* __restrict__ hlO, int c0)
{
    const int eh   = blockIdx.x;
    const int lc   = blockIdx.y;
    const int b    = blockIdx.z;
    const int c    = c0 + lc;
    const int tid  = threadIdx.x;
    const int lane = tid & 63;
    const int wv   = tid >> 6;
    const int n0   = eh * 256 + wv * 64;
    const int l15  = lane & 15;
    const int kg   = lane >> 4;

    const size_t rb = (size_t)(b * S_ + c * CT);

    f32x4 acc[2][4];
#pragma unroll
    for (int mf = 0; mf < 2; ++mf)
#pragma unroll
        for (int nf = 0; nf < 4; ++nf) acc[mf][nf] = (f32x4){0.f, 0.f, 0.f, 0.f};

    if (c > 0) {
        const unsigned short* cb = snap + ((size_t)(lc * 8 + b) * 512) * 512;
        const float* q0p = qkv + (rb + l15) * 1536;
        const float* q1p = qkv + (rb + 16 + l15) * 1536;
#pragma unroll 4
        for (int k0 = 0; k0 < 512; k0 += 32) {
            const int kb = k0 + kg * 8;
            bf16x8 a0 = cvt8(q0p + kb);
            bf16x8 a1 = cvt8(q1p + kb);
#pragma unroll
            for (int nf = 0; nf < 4; ++nf) {
                const unsigned short* bp = cb + (size_t)(n0 + nf * 16 + l15) * 512 + kb;
                bf16x8 bf = *(const bf16x8*)bp;
                acc[0][nf] = __builtin_amdgcn_mfma_f32_16x16x32_bf16(a0, bf, acc[0][nf], 0, 0, 0);
                acc[1][nf] = __builtin_amdgcn_mfma_f32_16x16x32_bf16(a1, bf, acc[1][nf], 0, 0, 0);
            }
        }
    }

    const float* ivp = invd + (size_t)b * S_ + c * CT;
#pragma unroll
    for (int mf = 0; mf < 2; ++mf) {
#pragma unroll
        for (int vi = 0; vi < 4; ++vi) {
            const int tl  = mf * 16 + kg * 4 + vi;
            const float ivt = ivp[tl];
            float* hrow       = hs + (rb + tl) * 512;
            const float* orow = gg + (rb + tl) * 1536 + 1024;
            const bool last = (c * CT + tl == S_ - 1);
#pragma unroll
            for (int nf = 0; nf < 4; ++nf) {
                const int e  = n0 + nf * 16 + l15;
                const float h1 = hrow[e];
                const float ov = orow[e];
                const float r  = (acc[mf][nf][vi] + h1) * ov * ivt;
                hrow[e] = r;
                if (last) hlO[(size_t)b * 512 + e] = r;
            }
        }
    }
}

// ---------------------------------------------------------------------------
extern "C" void kernel_launch(void* const* d_in, const int* in_sizes, int n_in,
                              void* d_out, int out_size, void* d_ws, size_t ws_size,
                              hipStream_t stream)
{
    const float* x    = (const float*)d_in[0];
    const float* W_in = (const float*)d_in[1];
    const float* b_in = (const float*)d_in[2];
    const float* W_ig = (const float*)d_in[3];
    const float* b_ig = (const float*)d_in[4];
    const float* W_fg = (const float*)d_in[5];
    const float* b_fg = (const float*)d_in[6];
    const float* W_og = (const float*)d_in[7];
    const float* b_og = (const float*)d_in[8];
    const float* W_out= (const float*)d_in[9];
    const float* b_out= (const float*)d_in[10];

    float* out   = (float*)d_out;                       // [8,1024,512]
    float* CfO   = out + (size_t)8 * 1024 * 512;        // [8,512,512]
    float* nfO   = CfO + (size_t)8 * 512 * 512;         // [8,512]
    float* hlO   = nfO + (size_t)8 * 512;               // [8,512]

    float* qkv = (float*)d_ws;                          // [8192,1536]
    float* gg  = qkv + (size_t)8192 * 1536;             // [8192,1536]
    float* hsb = gg  + (size_t)8192 * 1536;             // [8192,512]
    double* nend = (double*)hsb;                        // overlay (dead later)
    double* Dend = nend + (size_t)8 * NDCH * 512;
    double* n0a  = Dend + (size_t)8 * NDCH * 512;
    float*  invd = hsb + (size_t)8192 * 512;            // [8,1024]
    float*  Cst  = invd + 8192;                         // [8,512,512] f32
    unsigned short* Wh = (unsigned short*)(Cst + (size_t)8 * 512 * 512); // [3584][512]
    unsigned short* Wl = Wh + (size_t)3584 * 512;
    unsigned short* snap = Wl + (size_t)3584 * 512;

    const size_t WSB   = (size_t)((char*)snap - (char*)d_ws);   // bytes thru Wt
    const size_t SNAPC = (size_t)8 * 512 * 512 * 2;             // 4 MB / slot
    int nc; unsigned short* Ah;
    if (ws_size >= WSB + 32 * SNAPC)      { nc = 32; Ah = snap; }
    else if (ws_size >= WSB + 8 * SNAPC)  { nc = 8;  Ah = snap; }
    else                                  { nc = 2;  Ah = snap + 2 * (SNAPC / 2); }
    unsigned short* Al = Ah + (size_t)8192 * 512;

    // 0. weights -> bf16 hi/lo, tiled-swizzled [n][k] layout (persistent)
    prep_w<<<dim3(14, 16), 256, 0, stream>>>(W_in, W_ig, W_fg, W_og, W_out, Wh, Wl);
    // 1. proj + tanh(q,k):  qkv = act(x @ W_in[:, :1536])
    cvt_a<<<dim3(32, 16), 256, 0, stream>>>(x, 512, Ah, Al);
    gemm_mfma<0><<<1536, 128, 0, stream>>>(
        Ah, Al, Wh, Wl, qkv, b_in, b_in, b_in, qkv, 1536);
    // 2. gates: gg = [i*k | f | o]
    cvt_a<<<dim3(32, 16), 256, 0, stream>>>(qkv + 1024, 1536, Ah, Al);
    gemm_mfma<1><<<1536, 128, 0, stream>>>(
        Ah, Al, Wh, Wl, qkv, b_ig, b_fg, b_og, gg, 1536);
    // 3. f64 denominators on ORIGINAL q/ik/f
    nscan_local <<<1024, 512, 0, stream>>>(gg, nend, Dend);
    nscan_stitch<<<   8, 512, 0, stream>>>(nend, Dend, n0a, nfO);
    denom_kernel<<< 256, 256, 0, stream>>>(qkv, gg, n0a, invd);
    // 4. chunk transforms + intra-chunk H1
    chunk_prep<<<256, 512, 0, stream>>>(qkv, gg);
    chunk_A<<<256, 256, 0, stream>>>(qkv, gg, hsb);
    // 5. chunk recurrence (Acvt in snap region is dead from here on)
    for (int c0 = 0; c0 < NCT; c0 += nc) {
        chunk_cacc <<<dim3(8, nc, 2), 1024, 0, stream>>>(qkv, gg, snap, c0);
        chunk_cscan<<<dim3(8, 32, 2), 256, 0, stream>>>(gg, snap, Cst, CfO, c0, nc);
        chunk_h2   <<<dim3(2, nc, 8), 256, 0, stream>>>(qkv, gg, snap, invd, hsb, hlO, c0);
    }
    // 6. out = hs @ W_out + b_out   (snap dead -> Acvt reuse safe)
    cvt_a<<<dim3(32, 16), 256, 0, stream>>>(hsb, 512, Ah, Al);
    gemm_mfma<2><<<512, 128, 0, stream>>>(
        Ah, Al, Wh, Wl, qkv, b_out, b_out, b_out, out, 512);
}

// Round 17
// 433.042 us; speedup vs baseline: 1.0491x; 1.0491x over previous
//
#include <hip/hip_runtime.h>

#define S_ 1024
#define D_ 512
#define DCH 4       // denom chunk length (f64 pipeline)
#define NDCH 256    // denom chunks per batch
#define CT 32       // GEMM-scan chunk length
#define NCT 32      // GEMM-scan chunks per batch

using bf16x8 = __attribute__((ext_vector_type(8))) short;
using f32x4  = __attribute__((ext_vector_type(4))) float;

__device__ __forceinline__ unsigned short f2bf(float x) {
    unsigned int u = __float_as_uint(x);
    u = (u + 0x7FFFu + ((u >> 16) & 1u)) >> 16;
    return (unsigned short)u;
}
__device__ __forceinline__ float bf2f(unsigned short s) {
    return __uint_as_float(((unsigned int)s) << 16);
}
__device__ __forceinline__ bf16x8 cvt8(const float* __restrict__ p) {
    float4 a = *(const float4*)p;
    float4 b = *(const float4*)(p + 4);
    bf16x8 r;
    r[0] = (short)f2bf(a.x); r[1] = (short)f2bf(a.y);
    r[2] = (short)f2bf(a.z); r[3] = (short)f2bf(a.w);
    r[4] = (short)f2bf(b.x); r[5] = (short)f2bf(b.y);
    r[6] = (short)f2bf(b.z); r[7] = (short)f2bf(b.w);
    return r;
}
__device__ __forceinline__ void gload_lds16(const void* g, void* l) {
    __builtin_amdgcn_global_load_lds(
        (const __attribute__((address_space(1))) void*)g,
        (__attribute__((address_space(3))) void*)l, 16, 0, 0);
}

// Tiled-swizzled bf16 operand layout (cvt_a / prep_w / gemm_mfma):
// tile = (rowblk = row>>7, kblk = k>>5), 4096 elems (8 KB).
// within tile: elem = (row&127)*32 + (((k>>3)&3 ^ ((row>>1)&3))<<3) + (k&7)
// perm = (row>>1)&3 -> conflict-free ds_read_b128 (verified R15: conflicts=0).

// ---------------------------------------------------------------------------
// prep_w: weights -> bf16 hi/lo in tiled-swizzled [n][k] layout.
// ---------------------------------------------------------------------------
__global__ __launch_bounds__(256)
void prep_w(const float* __restrict__ W_in, const float* __restrict__ W_ig,
            const float* __restrict__ W_fg, const float* __restrict__ W_og,
            const float* __restrict__ W_out,
            unsigned short* __restrict__ Wh, unsigned short* __restrict__ Wl)
{
    const int n    = blockIdx.x * 256 + threadIdx.x;   // 0..3583
    const int kblk = blockIdx.y;                        // 0..15

    const float* src; int ldw, col;
    if (n < 1536)       { src = W_in;  ldw = 2048; col = n; }
    else if (n < 3072)  {
        const int g = (n - 1536) >> 9;
        src = (g == 0) ? W_ig : (g == 1) ? W_fg : W_og;
        ldw = 512; col = (n - 1536) & 511;
    } else              { src = W_out; ldw = 512; col = n - 3072; }

    unsigned int hw[16], lw[16];
#pragma unroll
    for (int j = 0; j < 32; j += 2) {
        const int k = kblk * 32 + j;
        float f0 = src[(size_t)k * ldw + col];
        float f1 = src[(size_t)(k + 1) * ldw + col];
        unsigned short h0 = f2bf(f0), h1 = f2bf(f1);
        unsigned short l0 = f2bf(f0 - bf2f(h0)), l1 = f2bf(f1 - bf2f(h1));
        hw[j >> 1] = (unsigned int)h0 | ((unsigned int)h1 << 16);
        lw[j >> 1] = (unsigned int)l0 | ((unsigned int)l1 << 16);
    }
    const size_t base = ((size_t)(n >> 7) * 16 + kblk) * 4096 + ((n & 127) << 5);
    const int perm = (n >> 1) & 3;
#pragma unroll
    for (int g = 0; g < 4; ++g) {
        const size_t dst = base + (size_t)((g ^ perm) << 3);
        *(uint4*)(Wh + dst) = make_uint4(hw[g*4], hw[g*4+1], hw[g*4+2], hw[g*4+3]);
        *(uint4*)(Wl + dst) = make_uint4(lw[g*4], lw[g*4+1], lw[g*4+2], lw[g*4+3]);
    }
}

// ---------------------------------------------------------------------------
// cvt_a: A f32 (row stride lda) -> bf16 hi/lo tiled-swizzled.
// ---------------------------------------------------------------------------
__global__ __launch_bounds__(256)
void cvt_a(const float* __restrict__ A, int lda,
           unsigned short* __restrict__ Ah, unsigned short* __restrict__ Al)
{
    const int m    = blockIdx.x * 256 + threadIdx.x;   // 0..8191
    const int kblk = blockIdx.y;                        // 0..15
    const float* p = A + (size_t)m * lda + kblk * 32;
    const size_t base = ((size_t)(m >> 7) * 16 + kblk) * 4096 + ((m & 127) << 5);
    const int perm = (m >> 1) & 3;
#pragma unroll
    for (int g = 0; g < 4; ++g) {
        float4 a = *(const float4*)(p + g * 8);
        float4 b = *(const float4*)(p + g * 8 + 4);
        float f[8] = {a.x, a.y, a.z, a.w, b.x, b.y, b.z, b.w};
        unsigned int hw[4], lw[4];
#pragma unroll
        for (int j = 0; j < 4; ++j) {
            unsigned short h0 = f2bf(f[2*j]), h1 = f2bf(f[2*j+1]);
            unsigned short l0 = f2bf(f[2*j] - bf2f(h0));
            unsigned short l1 = f2bf(f[2*j+1] - bf2f(h1));
            hw[j] = (unsigned int)h0 | ((unsigned int)h1 << 16);
            lw[j] = (unsigned int)l0 | ((unsigned int)l1 << 16);
        }
        const size_t dst = base + (size_t)((g ^ perm) << 3);
        *(uint4*)(Ah + dst) = make_uint4(hw[0], hw[1], hw[2], hw[3]);
        *(uint4*)(Al + dst) = make_uint4(lw[0], lw[1], lw[2], lw[3]);
    }
}

// ---------------------------------------------------------------------------
// gemm_mfma<MODE>: m97-structure bfx3 MFMA GEMM (exact R15 config: 256 thr,
// 4 waves 2x2 of 64x64, BM=BN=128, BK=32, 64 KB LDS dbuf, conflict-free).
// MODE 0: nbase 0,    nbt 12, ldc 1536, tanh n<1024; if Av: also emit
//         bf16 hi/lo split of v (n>=1024) in tiled-swizzled layout.
// MODE 1: nbase 1536, nbt 12, ldc 1536, sigmoid, n<512 fused *k
// MODE 2: nbase 3072, nbt 4,  ldc 512,  none
// ---------------------------------------------------------------------------
template<int MODE>
__global__ __launch_bounds__(256)
void gemm_mfma(const unsigned short* __restrict__ Ah,
               const unsigned short* __restrict__ Al,
               const unsigned short* __restrict__ Wh,
               const unsigned short* __restrict__ Wl,
               const float* __restrict__ qkv,
               const float* __restrict__ bb0, const float* __restrict__ bb1,
               const float* __restrict__ bb2,
               float* __restrict__ Co, int ldc,
               unsigned short* __restrict__ Av, unsigned short* __restrict__ Alv)
{
    __shared__ unsigned short lds[2][4][4096];   // [buf][Ah,Al,Wh,Wl][tile]

    const int tid  = threadIdx.x;
    const int lane = tid & 63;
    const int wv   = tid >> 6;
    const int nbt  = (MODE == 2) ? 4 : 12;
    const int cpx  = gridDim.x >> 3;                  // grid % 8 == 0
    const int swz  = (blockIdx.x & 7) * cpx + (blockIdx.x >> 3);
    const int n0blk = swz % nbt;
    const int m0blk = swz / nbt;
    const int l15  = lane & 15;
    const int kg   = lane >> 4;
    const int nbase = (MODE == 0) ? 0 : (MODE == 1) ? 1536 : 3072;

    const size_t abase = (size_t)m0blk * 16 * 4096;
    const size_t wbase = (size_t)((nbase >> 7) + n0blk) * 16 * 4096;

    f32x4 acc[4][4];
#pragma unroll
    for (int mf = 0; mf < 4; ++mf)
#pragma unroll
        for (int nf = 0; nf < 4; ++nf) acc[mf][nf] = (f32x4){0.f, 0.f, 0.f, 0.f};

    auto STAGE = [&](int buf, int kblk) {
        const unsigned short* srcs[4] = {
            Ah + abase + (size_t)kblk * 4096, Al + abase + (size_t)kblk * 4096,
            Wh + wbase + (size_t)kblk * 4096, Wl + wbase + (size_t)kblk * 4096};
#pragma unroll
        for (int p = 0; p < 4; ++p)
#pragma unroll
            for (int h = 0; h < 2; ++h)
                gload_lds16(srcs[p] + h * 2048 + (size_t)tid * 8,
                            &lds[buf][p][h * 2048 + wv * 512]);
    };

    STAGE(0, 0);
    __syncthreads();

    int cur = 0;
    for (int ks = 0; ks < 16; ++ks) {
        if (ks + 1 < 16) STAGE(cur ^ 1, ks + 1);

        bf16x8 ah[4], al[4], bh[4], bl[4];
#pragma unroll
        for (int i = 0; i < 4; ++i) {
            const int ra = (wv >> 1) * 64 + i * 16 + l15;
            const int oa = ra * 32 + ((kg ^ ((ra >> 1) & 3)) << 3);
            ah[i] = *(const bf16x8*)&lds[cur][0][oa];
            al[i] = *(const bf16x8*)&lds[cur][1][oa];
            const int rw = (wv & 1) * 64 + i * 16 + l15;
            const int ow = rw * 32 + ((kg ^ ((rw >> 1) & 3)) << 3);
            bh[i] = *(const bf16x8*)&lds[cur][2][ow];
            bl[i] = *(const bf16x8*)&lds[cur][3][ow];
        }
#pragma unroll
        for (int nf = 0; nf < 4; ++nf)
#pragma unroll
            for (int mf = 0; mf < 4; ++mf) {
                acc[mf][nf] = __builtin_amdgcn_mfma_f32_16x16x32_bf16(ah[mf], bh[nf], acc[mf][nf], 0, 0, 0);
                acc[mf][nf] = __builtin_amdgcn_mfma_f32_16x16x32_bf16(al[mf], bh[nf], acc[mf][nf], 0, 0, 0);
                acc[mf][nf] = __builtin_amdgcn_mfma_f32_16x16x32_bf16(ah[mf], bl[nf], acc[mf][nf], 0, 0, 0);
            }
        __syncthreads();
        cur ^= 1;
    }

    const int m0 = m0blk * 128 + (wv >> 1) * 64;
    const int n0 = n0blk * 128 + (wv & 1) * 64;
#pragma unroll
    for (int mf = 0; mf < 4; ++mf) {
#pragma unroll
        for (int vi = 0; vi < 4; ++vi) {
            const int m = m0 + mf * 16 + kg * 4 + vi;
            float* crow = Co + (size_t)m * ldc;
#pragma unroll
            for (int nf = 0; nf < 4; ++nf) {
                const int n = n0 + nf * 16 + l15;
                float bias;
                if (MODE == 1) {
                    const int g = n >> 9;
                    bias = (g == 0 ? bb0 : g == 1 ? bb1 : bb2)[n & 511];
                } else {
                    bias = bb0[n];
                }
                float v = acc[mf][nf][vi] + bias;
                if (MODE == 0) {
                    if (n < 1024) v = tanhf(v);
                } else if (MODE == 1) {
                    v = 1.0f / (1.0f + expf(-v));
                    if (n < 512) v *= qkv[(size_t)m * 1536 + 512 + n];
                }
                crow[n] = v;
                if (MODE == 0 && Av != nullptr && n >= 1024) {
                    // fused v -> bf16 hi/lo split, tiled-swizzled (== cvt_a)
                    const int k = n - 1024;
                    unsigned short h0 = f2bf(v);
                    unsigned short l0 = f2bf(v - bf2f(h0));
                    const size_t dst = ((size_t)(m >> 7) * 16 + (k >> 5)) * 4096
                                     + ((m & 127) << 5)
                                     + ((((k >> 3) & 3) ^ ((m >> 1) & 3)) << 3)
                                     + (k & 7);
                    Av[dst]  = h0;
                    Alv[dst] = l0;
                }
            }
        }
    }
}

// ---------------------------------------------------------------------------
// f64 denominator pipeline, DCH=4 (2x waves, half the serial chain vs R15)
// ---------------------------------------------------------------------------
__global__ __launch_bounds__(512)
void nscan_local(const float* __restrict__ GG,
                 double* __restrict__ nend, double* __restrict__ Dend)
{
    const int b = blockIdx.x >> 8;
    const int c = blockIdx.x & 255;
    const int d = threadIdx.x;
    const float* gb = GG + (size_t)b * S_ * 1536 + (size_t)c * DCH * 1536;
    double n = 0.0, P = 1.0;
    for (int u = 0; u < DCH; ++u) {
        const float* row = gb + (size_t)u * 1536;
        const double ik = (double)row[d];
        const double f  = (double)row[512 + d];
        n = fma(f, n, ik);
        P *= f;
    }
    nend[(size_t)blockIdx.x * 512 + d] = n;
    Dend[(size_t)blockIdx.x * 512 + d] = P;
}

__global__ __launch_bounds__(512)
void nscan_stitch(const double* __restrict__ nend, const double* __restrict__ Dend,
                  double* __restrict__ n0a, float* __restrict__ nfO)
{
    const int b = blockIdx.x;
    const int d = threadIdx.x;
    double n0 = 0.0;
    for (int c = 0; c < NDCH; ++c) {
        const size_t idx = ((size_t)(b * NDCH + c)) * 512 + d;
        n0a[idx] = n0;
        n0 = fma(Dend[idx], n0, nend[idx]);
    }
    nfO[(size_t)b * 512 + d] = (float)n0;
}

__global__ __launch_bounds__(256)
void denom_kernel(const float* __restrict__ QKV, const float* __restrict__ GG,
                  const double* __restrict__ n0a, float* __restrict__ invd)
{
    const int lane = threadIdx.x & 63;
    const int widx = blockIdx.x * 4 + (threadIdx.x >> 6);
    const int b    = widx >> 8;
    const int c    = widx & 255;
    const int d0   = 4 * lane;

    const float* qb = QKV + (size_t)b * S_ * 1536 + (size_t)c * DCH * 1536;
    const float* gb = GG  + (size_t)b * S_ * 1536 + (size_t)c * DCH * 1536;
    const double* sp = n0a + (size_t)widx * 512;

    double n[2][4];
#pragma unroll
    for (int r = 0; r < 2; ++r) {
        double2 a = *(const double2*)(sp + d0 + 256 * r);
        double2 bb = *(const double2*)(sp + d0 + 256 * r + 2);
        n[r][0] = a.x; n[r][1] = a.y; n[r][2] = bb.x; n[r][3] = bb.y;
    }

    for (int t0 = 0; t0 < DCH; t0 += 4) {
        double dq[4];
#pragma unroll
        for (int i = 0; i < 4; ++i) {
            const float* qr = qb + (size_t)(t0 + i) * 1536;
            const float* gr = gb + (size_t)(t0 + i) * 1536;
            double acc = 0.0;
#pragma unroll
            for (int r = 0; r < 2; ++r) {
                float4 qf = *(const float4*)(qr + d0 + 256 * r);
                float4 kf = *(const float4*)(gr + d0 + 256 * r);
                float4 ff = *(const float4*)(gr + 512 + d0 + 256 * r);
                const float* qp = (const float*)&qf;
                const float* kp = (const float*)&kf;
                const float* fp = (const float*)&ff;
#pragma unroll
                for (int j = 0; j < 4; ++j) {
                    n[r][j] = fma((double)fp[j], n[r][j], (double)kp[j]);
                    acc = fma((double)qp[j], n[r][j], acc);
                }
            }
            dq[i] = acc;
        }
        double u0 = dq[0] + __shfl_xor(dq[0], 32);
        double u1 = dq[1] + __shfl_xor(dq[1], 32);
        double u2 = dq[2] + __shfl_xor(dq[2], 32);
        double u3 = dq[3] + __shfl_xor(dq[3], 32);
        double w0 = (lane & 32) ? u2 : u0;
        double w1 = (lane & 32) ? u3 : u1;
        w0 += __shfl_xor(w0, 16);
        w1 += __shfl_xor(w1, 16);
        double y = (lane & 16) ? w1 : w0;
        y += __shfl_xor(y, 8); y += __shfl_xor(y, 4);
        y += __shfl_xor(y, 2); y += __shfl_xor(y, 1);
        if ((lane & 15) == 0) {
            const int g = lane >> 4;
            const double den = (y > 1e-6) ? y : 1e-6;
            invd[(size_t)b * S_ + c * DCH + t0 + g] = (float)(1.0 / den);
        }
    }
}

// ---------------------------------------------------------------------------
// chunk_prep (unchanged)
// ---------------------------------------------------------------------------
__global__ __launch_bounds__(512)
void chunk_prep(float* __restrict__ qkv, float* __restrict__ gg)
{
    const int b = blockIdx.x >> 5;
    const int c = blockIdx.x & 31;
    const int d = threadIdx.x;
    float* qr = qkv + ((size_t)(b * S_ + c * CT)) * 1536 + d;
    float* gr = gg  + ((size_t)(b * S_ + c * CT)) * 1536 + d;
    float* ft = gr + 512;
    float F = 1.f;
    for (int u = 0; u < CT; ++u) {
        const float q = qr[0], ik = gr[0], f = gr[512];
        F *= f;
        qr[0] = q * F;
        gr[0] = ik / F;
        qr += 1536; gr += 1536;
    }
    ft[0] = F;
}

// ---------------------------------------------------------------------------
// chunk_A (unchanged): H1 = tril(Qt Kt^T) V -> hsb
// ---------------------------------------------------------------------------
__global__ __launch_bounds__(256)
void chunk_A(const float* __restrict__ qkv, const float* __restrict__ gg,
             float* __restrict__ h1out)
{
    const int b   = blockIdx.x >> 5;
    const int c   = blockIdx.x & 31;
    const int tid = threadIdx.x;
    const int t   = tid & 31;
    const int g   = tid >> 5;

    __shared__ float sA[32][33];

    const size_t rb = (size_t)(b * S_ + c * CT);
    const float* qr = qkv + (rb + t) * 1536;
    const float* kb = gg + rb * 1536;

    {
        const int s0 = g * 4;
        const float* k0 = kb + (size_t)(s0 + 0) * 1536;
        const float* k1 = kb + (size_t)(s0 + 1) * 1536;
        const float* k2 = kb + (size_t)(s0 + 2) * 1536;
        const float* k3 = kb + (size_t)(s0 + 3) * 1536;
        float a0 = 0.f, a1 = 0.f, a2 = 0.f, a3 = 0.f;
        for (int d4 = 0; d4 < 512; d4 += 4) {
            float4 qv = *(const float4*)(qr + d4);
            float4 x0 = *(const float4*)(k0 + d4);
            float4 x1 = *(const float4*)(k1 + d4);
            float4 x2 = *(const float4*)(k2 + d4);
            float4 x3 = *(const float4*)(k3 + d4);
            a0 = fmaf(qv.x, x0.x, a0); a0 = fmaf(qv.y, x0.y, a0);
            a0 = fmaf(qv.z, x0.z, a0); a0 = fmaf(qv.w, x0.w, a0);
            a1 = fmaf(qv.x, x1.x, a1); a1 = fmaf(qv.y, x1.y, a1);
            a1 = fmaf(qv.z, x1.z, a1); a1 = fmaf(qv.w, x1.w, a1);
            a2 = fmaf(qv.x, x2.x, a2); a2 = fmaf(qv.y, x2.y, a2);
            a2 = fmaf(qv.z, x2.z, a2); a2 = fmaf(qv.w, x2.w, a2);
            a3 = fmaf(qv.x, x3.x, a3); a3 = fmaf(qv.y, x3.y, a3);
            a3 = fmaf(qv.z, x3.z, a3); a3 = fmaf(qv.w, x3.w, a3);
        }
        sA[t][s0 + 0] = (s0 + 0 <= t) ? a0 : 0.f;
        sA[t][s0 + 1] = (s0 + 1 <= t) ? a1 : 0.f;
        sA[t][s0 + 2] = (s0 + 2 <= t) ? a2 : 0.f;
        sA[t][s0 + 3] = (s0 + 3 <= t) ? a3 : 0.f;
    }
    __syncthreads();

    {
        const int e0 = g * 64;
        float4 h[16];
#pragma unroll
        for (int m = 0; m < 16; ++m) h[m] = make_float4(0.f, 0.f, 0.f, 0.f);
        const float* vb = qkv + rb * 1536 + 1024 + e0;
        for (int s = 0; s < CT; ++s) {
            const float a = sA[t][s];
            const float* vr = vb + (size_t)s * 1536;
#pragma unroll
            for (int m = 0; m < 16; ++m) {
                float4 vv = *(const float4*)(vr + m * 4);
                h[m].x = fmaf(a, vv.x, h[m].x);
                h[m].y = fmaf(a, vv.y, h[m].y);
                h[m].z = fmaf(a, vv.z, h[m].z);
                h[m].w = fmaf(a, vv.w, h[m].w);
            }
        }
        float* orow = h1out + (rb + t) * 512 + e0;
#pragma unroll
        for (int m = 0; m < 16; ++m) *(float4*)(orow + m * 4) = h[m];
    }
}

// ---------------------------------------------------------------------------
// chunk_cacc (unchanged): MFMA Cacc via LDS-transposed staging
// ---------------------------------------------------------------------------
__global__ __launch_bounds__(1024)
void chunk_cacc(const float* __restrict__ qkv, const float* __restrict__ gg,
                unsigned short* __restrict__ snap, int c0)
{
    __shared__ unsigned short vT[256][40];   // [e][u], padded pitch 40
    __shared__ unsigned short kT[512][40];   // [d][u]

    const int b    = blockIdx.x;
    const int lc   = blockIdx.y;
    const int eh   = blockIdx.z;
    const int c    = c0 + lc;
    const int tid  = threadIdx.x;
    const int lane = tid & 63;
    const int wv   = tid >> 6;          // 0..15
    const int l15  = lane & 15;
    const int kg   = lane >> 4;

    const size_t rb = (size_t)(b * S_ + c * CT);
    const size_t sb = ((size_t)lc * 8 + b) * 512;

    if (tid < 256) {
        const float* vp = qkv + rb * 1536 + 1024 + eh * 256 + tid;
        unsigned int pk[16];
#pragma unroll
        for (int u = 0; u < 32; u += 2) {
            float f0 = vp[(size_t)u * 1536];
            float f1 = vp[(size_t)(u + 1) * 1536];
            pk[u >> 1] = (unsigned int)f2bf(f0) | ((unsigned int)f2bf(f1) << 16);
        }
        uint4* dst = (uint4*)&vT[tid][0];
        dst[0] = make_uint4(pk[0],  pk[1],  pk[2],  pk[3]);
        dst[1] = make_uint4(pk[4],  pk[5],  pk[6],  pk[7]);
        dst[2] = make_uint4(pk[8],  pk[9],  pk[10], pk[11]);
        dst[3] = make_uint4(pk[12], pk[13], pk[14], pk[15]);
    } else if (tid < 768) {
        const int d = tid - 256;
        const float* kp = gg + rb * 1536 + d;
        unsigned int pk[16];
#pragma unroll
        for (int u = 0; u < 32; u += 2) {
            float f0 = kp[(size_t)u * 1536];
            float f1 = kp[(size_t)(u + 1) * 1536];
            pk[u >> 1] = (unsigned int)f2bf(f0) | ((unsigned int)f2bf(f1) << 16);
        }
        uint4* dst = (uint4*)&kT[d][0];
        dst[0] = make_uint4(pk[0],  pk[1],  pk[2],  pk[3]);
        dst[1] = make_uint4(pk[4],  pk[5],  pk[6],  pk[7]);
        dst[2] = make_uint4(pk[8],  pk[9],  pk[10], pk[11]);
        dst[3] = make_uint4(pk[12], pk[13], pk[14], pk[15]);
    }
    __syncthreads();

    const int ebase = (wv & 3) * 64;
    const int dbase = (wv >> 2) * 128;

    bf16x8 a[4];
#pragma unroll
    for (int me = 0; me < 4; ++me)
        a[me] = *(const bf16x8*)&vT[ebase + me * 16 + l15][kg * 8];

#pragma unroll
    for (int dp = 0; dp < 2; ++dp) {
        f32x4 acc[4][4];
#pragma unroll
        for (int me = 0; me < 4; ++me)
#pragma unroll
            for (int nd = 0; nd < 4; ++nd) acc[me][nd] = (f32x4){0.f, 0.f, 0.f, 0.f};

#pragma unroll
        for (int nd = 0; nd < 4; ++nd) {
            bf16x8 bfr = *(const bf16x8*)&kT[dbase + dp * 64 + nd * 16 + l15][kg * 8];
#pragma unroll
            for (int me = 0; me < 4; ++me)
                acc[me][nd] = __builtin_amdgcn_mfma_f32_16x16x32_bf16(a[me], bfr, acc[me][nd], 0, 0, 0);
        }

#pragma unroll
        for (int me = 0; me < 4; ++me)
#pragma unroll
            for (int vi = 0; vi < 4; ++vi) {
                const int e = eh * 256 + ebase + me * 16 + kg * 4 + vi;
                unsigned short* row = snap + (sb + e) * 512 + dbase + dp * 64;
#pragma unroll
                for (int nd = 0; nd < 4; ++nd)
                    row[nd * 16 + l15] = f2bf(acc[me][nd][vi]);
            }
    }
}

// ---------------------------------------------------------------------------
// chunk_cscan (unchanged): 32-step elementwise scan, snapshots in place
// ---------------------------------------------------------------------------
__global__ __launch_bounds__(256)
void chunk_cscan(const float* __restrict__ gg,
                 unsigned short* __restrict__ snap, float* __restrict__ Cst,
                 float* __restrict__ CfO, int c0, int nc)
{
    const int tid  = threadIdx.x;
    const int lane = tid & 63;
    const int wv   = tid >> 6;
    const int b    = blockIdx.x;
    const int eg   = blockIdx.y;
    const int dh   = blockIdx.z;
    const int ew   = eg * 16 + wv * 4;
    const int d0   = dh * 256 + 4 * lane;

    const float* gb = gg + (size_t)b * S_ * 1536;

    float C[4][4];
    if (c0 == 0) {
#pragma unroll
        for (int i = 0; i < 4; ++i)
#pragma unroll
            for (int j = 0; j < 4; ++j) C[i][j] = 0.f;
    } else {
#pragma unroll
        for (int j = 0; j < 4; ++j) {
            float4 cv = *(const float4*)&Cst[((size_t)b * 512 + d0 + j) * 512 + ew];
            C[0][j] = cv.x; C[1][j] = cv.y; C[2][j] = cv.z; C[3][j] = cv.w;
        }
    }

    ushort4 A0[4]; float4 F0;
    {
        const size_t sb = ((size_t)0 * 8 + b) * 512;
#pragma unroll
        for (int i = 0; i < 4; ++i)
            A0[i] = *(const ushort4*)(snap + (sb + ew + i) * 512 + d0);
        F0 = *(const float4*)(gb + (size_t)(c0 * CT) * 1536 + 512 + d0);
    }

    for (int lc = 0; lc < nc; ++lc) {
        ushort4 A1[4]; float4 F1;
        if (lc + 1 < nc) {
            const size_t sb = ((size_t)(lc + 1) * 8 + b) * 512;
#pragma unroll
            for (int i = 0; i < 4; ++i)
                A1[i] = *(const ushort4*)(snap + (sb + ew + i) * 512 + d0);
            F1 = *(const float4*)(gb + (size_t)((c0 + lc + 1) * CT) * 1536 + 512 + d0);
        }

        const int c = c0 + lc;
        if (c > 0) {
            const size_t sb = ((size_t)lc * 8 + b) * 512;
#pragma unroll
            for (int i = 0; i < 4; ++i) {
                uint2 pk;
                pk.x = (unsigned int)f2bf(C[i][0]) | ((unsigned int)f2bf(C[i][1]) << 16);
                pk.y = (unsigned int)f2bf(C[i][2]) | ((unsigned int)f2bf(C[i][3]) << 16);
                *(uint2*)(snap + (sb + ew + i) * 512 + d0) = pk;
            }
        }

        const float* fp = (const float*)&F0;
#pragma unroll
        for (int i = 0; i < 4; ++i) {
            C[i][0] = fp[0] * (C[i][0] + bf2f(A0[i].x));
            C[i][1] = fp[1] * (C[i][1] + bf2f(A0[i].y));
            C[i][2] = fp[2] * (C[i][2] + bf2f(A0[i].z));
            C[i][3] = fp[3] * (C[i][3] + bf2f(A0[i].w));
        }

        if (lc + 1 < nc) {
#pragma unroll
            for (int i = 0; i < 4; ++i) A0[i] = A1[i];
            F0 = F1;
        }
    }

    float* outp = (c0 + nc == NCT) ? CfO : Cst;
#pragma unroll
    for (int j = 0; j < 4; ++j)
        *(float4*)&outp[((size_t)b * 512 + d0 + j) * 512 + ew] =
            make_float4(C[0][j], C[1][j], C[2][j], C[3][j]);
}

// ---------------------------------------------------------------------------
// chunk_h2 (unchanged): H2 = Qt @ C0^T via mfma + fused combine epilogue
// ---------------------------------------------------------------------------
__global__ __launch_bounds__(256)
void chunk_h2(const float* __restrict__ qkv, const float* __restrict__ gg,
              const unsigned short* __restrict__ snap,
              const float* __restrict__ invd,
              float* __restrict__ hs, float* __restrict__ hlO, int c0)
{
    const int eh   = blockIdx.x;
    const int lc   = blockIdx.y;
    const int b    = blockIdx.z;
    const int c    = c0 + lc;
    const int tid  = threadIdx.x;
    const int lane = tid & 63;
    const int wv   = tid >> 6;
    const int n0   = eh * 256 + wv * 64;
    const int l15  = lane & 15;
    const int kg   = lane >> 4;

    const size_t rb = (size_t)(b * S_ + c * CT);

    f32x4 acc[2][4];
#pragma unroll
    for (int mf = 0; mf < 2; ++mf)
#pragma unroll
        for (int nf = 0; nf < 4; ++nf) acc[mf][nf] = (f32x4){0.f, 0.f, 0.f, 0.f};

    if (c > 0) {
        const unsigned short* cb = snap + ((size_t)(lc * 8 + b) * 512) * 512;
        const float* q0p = qkv + (rb + l15) * 1536;
        const float* q1p = qkv + (rb + 16 + l15) * 1536;
#pragma unroll 4
        for (int k0 = 0; k0 < 512; k0 += 32) {
            const int kb = k0 + kg * 8;
            bf16x8 a0 = cvt8(q0p + kb);
            bf16x8 a1 = cvt8(q1p + kb);
#pragma unroll
            for (int nf = 0; nf < 4; ++nf) {
                const unsigned short* bp = cb + (size_t)(n0 + nf * 16 + l15) * 512 + kb;
                bf16x8 bf = *(const bf16x8*)bp;
                acc[0][nf] = __builtin_amdgcn_mfma_f32_16x16x32_bf16(a0, bf, acc[0][nf], 0, 0, 0);
                acc[1][nf] = __builtin_amdgcn_mfma_f32_16x16x32_bf16(a1, bf, acc[1][nf], 0, 0, 0);
            }
        }
    }

    const float* ivp = invd + (size_t)b * S_ + c * CT;
#pragma unroll
    for (int mf = 0; mf < 2; ++mf) {
#pragma unroll
        for (int vi = 0; vi < 4; ++vi) {
            const int tl  = mf * 16 + kg * 4 + vi;
            const float ivt = ivp[tl];
            float* hrow       = hs + (rb + tl) * 512;
            const float* orow = gg + (rb + tl) * 1536 + 1024;
            const bool last = (c * CT + tl == S_ - 1);
#pragma unroll
            for (int nf = 0; nf < 4; ++nf) {
                const int e  = n0 + nf * 16 + l15;
                const float h1 = hrow[e];
                const float ov = orow[e];
                const float r  = (acc[mf][nf][vi] + h1) * ov * ivt;
                hrow[e] = r;
                if (last) hlO[(size_t)b * 512 + e] = r;
            }
        }
    }
}

// ---------------------------------------------------------------------------
extern "C" void kernel_launch(void* const* d_in, const int* in_sizes, int n_in,
                              void* d_out, int out_size, void* d_ws, size_t ws_size,
                              hipStream_t stream)
{
    const float* x    = (const float*)d_in[0];
    const float* W_in = (const float*)d_in[1];
    const float* b_in = (const float*)d_in[2];
    const float* W_ig = (const float*)d_in[3];
    const float* b_ig = (const float*)d_in[4];
    const float* W_fg = (const float*)d_in[5];
    const float* b_fg = (const float*)d_in[6];
    const float* W_og = (const float*)d_in[7];
    const float* b_og = (const float*)d_in[8];
    const float* W_out= (const float*)d_in[9];
    const float* b_out= (const float*)d_in[10];

    float* out   = (float*)d_out;                       // [8,1024,512]
    float* CfO   = out + (size_t)8 * 1024 * 512;        // [8,512,512]
    float* nfO   = CfO + (size_t)8 * 512 * 512;         // [8,512]
    float* hlO   = nfO + (size_t)8 * 512;               // [8,512]

    float* qkv = (float*)d_ws;                          // [8192,1536]
    float* gg  = qkv + (size_t)8192 * 1536;             // [8192,1536]
    float* hsb = gg  + (size_t)8192 * 1536;             // [8192,512]
    double* nend = (double*)hsb;                        // overlay (dead later)
    double* Dend = nend + (size_t)8 * NDCH * 512;
    double* n0a  = Dend + (size_t)8 * NDCH * 512;
    float*  invd = hsb + (size_t)8192 * 512;            // [8,1024]
    float*  Cst  = invd + 8192;                         // [8,512,512] f32
    unsigned short* Wh = (unsigned short*)(Cst + (size_t)8 * 512 * 512); // [3584][512]
    unsigned short* Wl = Wh + (size_t)3584 * 512;
    unsigned short* snap = Wl + (size_t)3584 * 512;

    const size_t WSB   = (size_t)((char*)snap - (char*)d_ws);   // bytes thru Wt
    const size_t SNAPC = (size_t)8 * 512 * 512 * 2;             // 4 MB / slot
    const size_t SLOTS = (size_t)8 * 512 * 512;                 // shorts / slot
    int nc; unsigned short* Ah;
    if (ws_size >= WSB + 32 * SNAPC)      { nc = 32; Ah = snap; }
    else if (ws_size >= WSB + 8 * SNAPC)  { nc = 8;  Ah = snap; }
    else                                  { nc = 2;  Ah = snap + 2 * (SNAPC / 2); }
    unsigned short* Al = Ah + (size_t)8192 * 512;

    // fused v-split destination (snap slots 4..7; safe while slots unused)
    unsigned short* Av  = nullptr;
    unsigned short* Alv = nullptr;
    if (nc >= 8) { Av = snap + 4 * SLOTS; Alv = Av + (size_t)8192 * 512; }

    // 0. weights -> bf16 hi/lo, tiled-swizzled [n][k] layout (persistent)
    prep_w<<<dim3(14, 16), 256, 0, stream>>>(W_in, W_ig, W_fg, W_og, W_out, Wh, Wl);
    // 1. proj + tanh(q,k):  qkv = act(x @ W_in[:, :1536]); fused v bf16 split
    cvt_a<<<dim3(32, 16), 256, 0, stream>>>(x, 512, Ah, Al);
    gemm_mfma<0><<<768, 256, 0, stream>>>(
        Ah, Al, Wh, Wl, qkv, b_in, b_in, b_in, qkv, 1536, Av, Alv);
    // 2. gates: gg = [i*k | f | o]
    const unsigned short* Aga = Av  ? Av  : Ah;
    const unsigned short* Agl = Alv ? Alv : Al;
    if (!Av) cvt_a<<<dim3(32, 16), 256, 0, stream>>>(qkv + 1024, 1536, Ah, Al);
    gemm_mfma<1><<<768, 256, 0, stream>>>(
        Aga, Agl, Wh, Wl, qkv, b_ig, b_fg, b_og, gg, 1536, nullptr, nullptr);
    // 3. f64 denominators on ORIGINAL q/ik/f
    nscan_local <<<2048, 512, 0, stream>>>(gg, nend, Dend);
    nscan_stitch<<<   8, 512, 0, stream>>>(nend, Dend, n0a, nfO);
    denom_kernel<<< 512, 256, 0, stream>>>(qkv, gg, n0a, invd);
    // 4. chunk transforms + intra-chunk H1
    chunk_prep<<<256, 512, 0, stream>>>(qkv, gg);
    chunk_A<<<256, 256, 0, stream>>>(qkv, gg, hsb);
    // 5. chunk recurrence (Acvt/Av in snap region dead from here on)
    for (int c0 = 0; c0 < NCT; c0 += nc) {
        chunk_cacc <<<dim3(8, nc, 2), 1024, 0, stream>>>(qkv, gg, snap, c0);
        chunk_cscan<<<dim3(8, 32, 2), 256, 0, stream>>>(gg, snap, Cst, CfO, c0, nc);
        chunk_h2   <<<dim3(2, nc, 8), 256, 0, stream>>>(qkv, gg, snap, invd, hsb, hlO, c0);
    }
    // 6. out = hs @ W_out + b_out   (snap dead -> Acvt reuse safe)
    cvt_a<<<dim3(32, 16), 256, 0, stream>>>(hsb, 512, Ah, Al);
    gemm_mfma<2><<<256, 256, 0, stream>>>(
        Ah, Al, Wh, Wl, qkv, b_out, b_out, b_out, out, 512, nullptr, nullptr);
}

// Round 18
// 375.356 us; speedup vs baseline: 1.2104x; 1.1537x over previous
//
#include <hip/hip_runtime.h>

#define S_ 1024
#define D_ 512
#define DCH 8       // denom chunk length (f64 pipeline)
#define NDCH 128    // denom chunks per batch
#define CT 32       // GEMM-scan chunk length
#define NCT 32      // GEMM-scan chunks per batch

using bf16x8 = __attribute__((ext_vector_type(8))) short;
using f32x4  = __attribute__((ext_vector_type(4))) float;

__device__ __forceinline__ unsigned short f2bf(float x) {
    unsigned int u = __float_as_uint(x);
    u = (u + 0x7FFFu + ((u >> 16) & 1u)) >> 16;
    return (unsigned short)u;
}
__device__ __forceinline__ float bf2f(unsigned short s) {
    return __uint_as_float(((unsigned int)s) << 16);
}
__device__ __forceinline__ bf16x8 cvt8(const float* __restrict__ p) {
    float4 a = *(const float4*)p;
    float4 b = *(const float4*)(p + 4);
    bf16x8 r;
    r[0] = (short)f2bf(a.x); r[1] = (short)f2bf(a.y);
    r[2] = (short)f2bf(a.z); r[3] = (short)f2bf(a.w);
    r[4] = (short)f2bf(b.x); r[5] = (short)f2bf(b.y);
    r[6] = (short)f2bf(b.z); r[7] = (short)f2bf(b.w);
    return r;
}
__device__ __forceinline__ void cvt8pair(const float* __restrict__ p,
                                         bf16x8& hi, bf16x8& lo) {
    float4 a = *(const float4*)p;
    float4 b = *(const float4*)(p + 4);
    float f[8] = {a.x, a.y, a.z, a.w, b.x, b.y, b.z, b.w};
#pragma unroll
    for (int j = 0; j < 8; ++j) {
        unsigned short h = f2bf(f[j]);
        hi[j] = (short)h;
        lo[j] = (short)f2bf(f[j] - bf2f(h));
    }
}
__device__ __forceinline__ void gload_lds16(const void* g, void* l) {
    __builtin_amdgcn_global_load_lds(
        (const __attribute__((address_space(1))) void*)g,
        (__attribute__((address_space(3))) void*)l, 16, 0, 0);
}

// Tiled-swizzled bf16 operand layout (cvt_a / prep_w / gemm_mfma):
// tile = (rowblk = row>>7, kblk = k>>5), 4096 elems (8 KB).
// within tile: elem = (row&127)*32 + (((k>>3)&3 ^ ((row>>1)&3))<<3) + (k&7)
// perm = (row>>1)&3 -> conflict-free ds_read_b128 (verified R15: conflicts=0).

// ---------------------------------------------------------------------------
// prep_w: weights -> bf16 hi/lo in tiled-swizzled [n][k] layout.
// ---------------------------------------------------------------------------
__global__ __launch_bounds__(256)
void prep_w(const float* __restrict__ W_in, const float* __restrict__ W_ig,
            const float* __restrict__ W_fg, const float* __restrict__ W_og,
            const float* __restrict__ W_out,
            unsigned short* __restrict__ Wh, unsigned short* __restrict__ Wl)
{
    const int n    = blockIdx.x * 256 + threadIdx.x;   // 0..3583
    const int kblk = blockIdx.y;                        // 0..15

    const float* src; int ldw, col;
    if (n < 1536)       { src = W_in;  ldw = 2048; col = n; }
    else if (n < 3072)  {
        const int g = (n - 1536) >> 9;
        src = (g == 0) ? W_ig : (g == 1) ? W_fg : W_og;
        ldw = 512; col = (n - 1536) & 511;
    } else              { src = W_out; ldw = 512; col = n - 3072; }

    unsigned int hw[16], lw[16];
#pragma unroll
    for (int j = 0; j < 32; j += 2) {
        const int k = kblk * 32 + j;
        float f0 = src[(size_t)k * ldw + col];
        float f1 = src[(size_t)(k + 1) * ldw + col];
        unsigned short h0 = f2bf(f0), h1 = f2bf(f1);
        unsigned short l0 = f2bf(f0 - bf2f(h0)), l1 = f2bf(f1 - bf2f(h1));
        hw[j >> 1] = (unsigned int)h0 | ((unsigned int)h1 << 16);
        lw[j >> 1] = (unsigned int)l0 | ((unsigned int)l1 << 16);
    }
    const size_t base = ((size_t)(n >> 7) * 16 + kblk) * 4096 + ((n & 127) << 5);
    const int perm = (n >> 1) & 3;
#pragma unroll
    for (int g = 0; g < 4; ++g) {
        const size_t dst = base + (size_t)((g ^ perm) << 3);
        *(uint4*)(Wh + dst) = make_uint4(hw[g*4], hw[g*4+1], hw[g*4+2], hw[g*4+3]);
        *(uint4*)(Wl + dst) = make_uint4(lw[g*4], lw[g*4+1], lw[g*4+2], lw[g*4+3]);
    }
}

// ---------------------------------------------------------------------------
// cvt_a: A f32 (row stride lda) -> bf16 hi/lo tiled-swizzled.
// ---------------------------------------------------------------------------
__global__ __launch_bounds__(256)
void cvt_a(const float* __restrict__ A, int lda,
           unsigned short* __restrict__ Ah, unsigned short* __restrict__ Al)
{
    const int m    = blockIdx.x * 256 + threadIdx.x;   // 0..8191
    const int kblk = blockIdx.y;                        // 0..15
    const float* p = A + (size_t)m * lda + kblk * 32;
    const size_t base = ((size_t)(m >> 7) * 16 + kblk) * 4096 + ((m & 127) << 5);
    const int perm = (m >> 1) & 3;
#pragma unroll
    for (int g = 0; g < 4; ++g) {
        float4 a = *(const float4*)(p + g * 8);
        float4 b = *(const float4*)(p + g * 8 + 4);
        float f[8] = {a.x, a.y, a.z, a.w, b.x, b.y, b.z, b.w};
        unsigned int hw[4], lw[4];
#pragma unroll
        for (int j = 0; j < 4; ++j) {
            unsigned short h0 = f2bf(f[2*j]), h1 = f2bf(f[2*j+1]);
            unsigned short l0 = f2bf(f[2*j] - bf2f(h0));
            unsigned short l1 = f2bf(f[2*j+1] - bf2f(h1));
            hw[j] = (unsigned int)h0 | ((unsigned int)h1 << 16);
            lw[j] = (unsigned int)l0 | ((unsigned int)l1 << 16);
        }
        const size_t dst = base + (size_t)((g ^ perm) << 3);
        *(uint4*)(Ah + dst) = make_uint4(hw[0], hw[1], hw[2], hw[3]);
        *(uint4*)(Al + dst) = make_uint4(lw[0], lw[1], lw[2], lw[3]);
    }
}

// ---------------------------------------------------------------------------
// gemm_mfma<MODE>: m97-structure bfx3 MFMA GEMM (R15 config, conflict-free).
// MODE 0: nbase 0,    nbt 12, ldc 1536, tanh n<1024; if Av: fused v bf16 split
// MODE 1: nbase 1536, nbt 12, ldc 1536, sigmoid, n<512 fused *k
// MODE 2: nbase 3072, nbt 4,  ldc 512,  none
// ---------------------------------------------------------------------------
template<int MODE>
__global__ __launch_bounds__(256)
void gemm_mfma(const unsigned short* __restrict__ Ah,
               const unsigned short* __restrict__ Al,
               const unsigned short* __restrict__ Wh,
               const unsigned short* __restrict__ Wl,
               const float* __restrict__ qkv,
               const float* __restrict__ bb0, const float* __restrict__ bb1,
               const float* __restrict__ bb2,
               float* __restrict__ Co, int ldc,
               unsigned short* __restrict__ Av, unsigned short* __restrict__ Alv)
{
    __shared__ unsigned short lds[2][4][4096];   // [buf][Ah,Al,Wh,Wl][tile]

    const int tid  = threadIdx.x;
    const int lane = tid & 63;
    const int wv   = tid >> 6;
    const int nbt  = (MODE == 2) ? 4 : 12;
    const int cpx  = gridDim.x >> 3;                  // grid % 8 == 0
    const int swz  = (blockIdx.x & 7) * cpx + (blockIdx.x >> 3);
    const int n0blk = swz % nbt;
    const int m0blk = swz / nbt;
    const int l15  = lane & 15;
    const int kg   = lane >> 4;
    const int nbase = (MODE == 0) ? 0 : (MODE == 1) ? 1536 : 3072;

    const size_t abase = (size_t)m0blk * 16 * 4096;
    const size_t wbase = (size_t)((nbase >> 7) + n0blk) * 16 * 4096;

    f32x4 acc[4][4];
#pragma unroll
    for (int mf = 0; mf < 4; ++mf)
#pragma unroll
        for (int nf = 0; nf < 4; ++nf) acc[mf][nf] = (f32x4){0.f, 0.f, 0.f, 0.f};

    auto STAGE = [&](int buf, int kblk) {
        const unsigned short* srcs[4] = {
            Ah + abase + (size_t)kblk * 4096, Al + abase + (size_t)kblk * 4096,
            Wh + wbase + (size_t)kblk * 4096, Wl + wbase + (size_t)kblk * 4096};
#pragma unroll
        for (int p = 0; p < 4; ++p)
#pragma unroll
            for (int h = 0; h < 2; ++h)
                gload_lds16(srcs[p] + h * 2048 + (size_t)tid * 8,
                            &lds[buf][p][h * 2048 + wv * 512]);
    };

    STAGE(0, 0);
    __syncthreads();

    int cur = 0;
    for (int ks = 0; ks < 16; ++ks) {
        if (ks + 1 < 16) STAGE(cur ^ 1, ks + 1);

        bf16x8 ah[4], al[4], bh[4], bl[4];
#pragma unroll
        for (int i = 0; i < 4; ++i) {
            const int ra = (wv >> 1) * 64 + i * 16 + l15;
            const int oa = ra * 32 + ((kg ^ ((ra >> 1) & 3)) << 3);
            ah[i] = *(const bf16x8*)&lds[cur][0][oa];
            al[i] = *(const bf16x8*)&lds[cur][1][oa];
            const int rw = (wv & 1) * 64 + i * 16 + l15;
            const int ow = rw * 32 + ((kg ^ ((rw >> 1) & 3)) << 3);
            bh[i] = *(const bf16x8*)&lds[cur][2][ow];
            bl[i] = *(const bf16x8*)&lds[cur][3][ow];
        }
#pragma unroll
        for (int nf = 0; nf < 4; ++nf)
#pragma unroll
            for (int mf = 0; mf < 4; ++mf) {
                acc[mf][nf] = __builtin_amdgcn_mfma_f32_16x16x32_bf16(ah[mf], bh[nf], acc[mf][nf], 0, 0, 0);
                acc[mf][nf] = __builtin_amdgcn_mfma_f32_16x16x32_bf16(al[mf], bh[nf], acc[mf][nf], 0, 0, 0);
                acc[mf][nf] = __builtin_amdgcn_mfma_f32_16x16x32_bf16(ah[mf], bl[nf], acc[mf][nf], 0, 0, 0);
            }
        __syncthreads();
        cur ^= 1;
    }

    const int m0 = m0blk * 128 + (wv >> 1) * 64;
    const int n0 = n0blk * 128 + (wv & 1) * 64;
#pragma unroll
    for (int mf = 0; mf < 4; ++mf) {
#pragma unroll
        for (int vi = 0; vi < 4; ++vi) {
            const int m = m0 + mf * 16 + kg * 4 + vi;
            float* crow = Co + (size_t)m * ldc;
#pragma unroll
            for (int nf = 0; nf < 4; ++nf) {
                const int n = n0 + nf * 16 + l15;
                float bias;
                if (MODE == 1) {
                    const int g = n >> 9;
                    bias = (g == 0 ? bb0 : g == 1 ? bb1 : bb2)[n & 511];
                } else {
                    bias = bb0[n];
                }
                float v = acc[mf][nf][vi] + bias;
                if (MODE == 0) {
                    if (n < 1024) v = tanhf(v);
                } else if (MODE == 1) {
                    v = 1.0f / (1.0f + expf(-v));
                    if (n < 512) v *= qkv[(size_t)m * 1536 + 512 + n];
                }
                crow[n] = v;
                if (MODE == 0 && Av != nullptr && n >= 1024) {
                    const int k = n - 1024;
                    unsigned short h0 = f2bf(v);
                    unsigned short l0 = f2bf(v - bf2f(h0));
                    const size_t dst = ((size_t)(m >> 7) * 16 + (k >> 5)) * 4096
                                     + ((m & 127) << 5)
                                     + ((((k >> 3) & 3) ^ ((m >> 1) & 3)) << 3)
                                     + (k & 7);
                    Av[dst]  = h0;
                    Alv[dst] = l0;
                }
            }
        }
    }
}

// ---------------------------------------------------------------------------
// f64 denominator pipeline (R15 config: DCH=8, NDCH=128)
// ---------------------------------------------------------------------------
__global__ __launch_bounds__(512)
void nscan_local(const float* __restrict__ GG,
                 double* __restrict__ nend, double* __restrict__ Dend)
{
    const int b = blockIdx.x >> 7;
    const int c = blockIdx.x & 127;
    const int d = threadIdx.x;
    const float* gb = GG + (size_t)b * S_ * 1536 + (size_t)c * DCH * 1536;
    double n = 0.0, P = 1.0;
    for (int u = 0; u < DCH; ++u) {
        const float* row = gb + (size_t)u * 1536;
        const double ik = (double)row[d];
        const double f  = (double)row[512 + d];
        n = fma(f, n, ik);
        P *= f;
    }
    nend[(size_t)blockIdx.x * 512 + d] = n;
    Dend[(size_t)blockIdx.x * 512 + d] = P;
}

__global__ __launch_bounds__(512)
void nscan_stitch(const double* __restrict__ nend, const double* __restrict__ Dend,
                  double* __restrict__ n0a, float* __restrict__ nfO)
{
    const int b = blockIdx.x;
    const int d = threadIdx.x;
    double n0 = 0.0;
    for (int c = 0; c < NDCH; ++c) {
        const size_t idx = ((size_t)(b * NDCH + c)) * 512 + d;
        n0a[idx] = n0;
        n0 = fma(Dend[idx], n0, nend[idx]);
    }
    nfO[(size_t)b * 512 + d] = (float)n0;
}

__global__ __launch_bounds__(256)
void denom_kernel(const float* __restrict__ QKV, const float* __restrict__ GG,
                  const double* __restrict__ n0a, float* __restrict__ invd)
{
    const int lane = threadIdx.x & 63;
    const int widx = blockIdx.x * 4 + (threadIdx.x >> 6);
    const int b    = widx >> 7;
    const int c    = widx & 127;
    const int d0   = 4 * lane;

    const float* qb = QKV + (size_t)b * S_ * 1536 + (size_t)c * DCH * 1536;
    const float* gb = GG  + (size_t)b * S_ * 1536 + (size_t)c * DCH * 1536;
    const double* sp = n0a + (size_t)widx * 512;

    double n[2][4];
#pragma unroll
    for (int r = 0; r < 2; ++r) {
        double2 a = *(const double2*)(sp + d0 + 256 * r);
        double2 bb = *(const double2*)(sp + d0 + 256 * r + 2);
        n[r][0] = a.x; n[r][1] = a.y; n[r][2] = bb.x; n[r][3] = bb.y;
    }

    for (int t0 = 0; t0 < DCH; t0 += 4) {
        double dq[4];
#pragma unroll
        for (int i = 0; i < 4; ++i) {
            const float* qr = qb + (size_t)(t0 + i) * 1536;
            const float* gr = gb + (size_t)(t0 + i) * 1536;
            double acc = 0.0;
#pragma unroll
            for (int r = 0; r < 2; ++r) {
                float4 qf = *(const float4*)(qr + d0 + 256 * r);
                float4 kf = *(const float4*)(gr + d0 + 256 * r);
                float4 ff = *(const float4*)(gr + 512 + d0 + 256 * r);
                const float* qp = (const float*)&qf;
                const float* kp = (const float*)&kf;
                const float* fp = (const float*)&ff;
#pragma unroll
                for (int j = 0; j < 4; ++j) {
                    n[r][j] = fma((double)fp[j], n[r][j], (double)kp[j]);
                    acc = fma((double)qp[j], n[r][j], acc);
                }
            }
            dq[i] = acc;
        }
        double u0 = dq[0] + __shfl_xor(dq[0], 32);
        double u1 = dq[1] + __shfl_xor(dq[1], 32);
        double u2 = dq[2] + __shfl_xor(dq[2], 32);
        double u3 = dq[3] + __shfl_xor(dq[3], 32);
        double w0 = (lane & 32) ? u2 : u0;
        double w1 = (lane & 32) ? u3 : u1;
        w0 += __shfl_xor(w0, 16);
        w1 += __shfl_xor(w1, 16);
        double y = (lane & 16) ? w1 : w0;
        y += __shfl_xor(y, 8); y += __shfl_xor(y, 4);
        y += __shfl_xor(y, 2); y += __shfl_xor(y, 1);
        if ((lane & 15) == 0) {
            const int g = lane >> 4;
            const double den = (y > 1e-6) ? y : 1e-6;
            invd[(size_t)b * S_ + c * DCH + t0 + g] = (float)(1.0 / den);
        }
    }
}

// ---------------------------------------------------------------------------
// chunk_prep (unchanged)
// ---------------------------------------------------------------------------
__global__ __launch_bounds__(512)
void chunk_prep(float* __restrict__ qkv, float* __restrict__ gg)
{
    const int b = blockIdx.x >> 5;
    const int c = blockIdx.x & 31;
    const int d = threadIdx.x;
    float* qr = qkv + ((size_t)(b * S_ + c * CT)) * 1536 + d;
    float* gr = gg  + ((size_t)(b * S_ + c * CT)) * 1536 + d;
    float* ft = gr + 512;
    float F = 1.f;
    for (int u = 0; u < CT; ++u) {
        const float q = qr[0], ik = gr[0], f = gr[512];
        F *= f;
        qr[0] = q * F;
        gr[0] = ik / F;
        qr += 1536; gr += 1536;
    }
    ft[0] = F;
}

// ---------------------------------------------------------------------------
// chunk_A (MFMA): per chunk, A = tril(Qt Kt^T) via bfx3 (4 wave-quadrants,
// fragments straight from global rows — verified chunk_h2 pattern), then
// H1 = A V via bfx3 with A hi/lo from LDS and V^T staged per 256-e half
// (verified chunk_cacc vT pattern).  grid 256 = (b, c), 256 thr.
// ---------------------------------------------------------------------------
__global__ __launch_bounds__(256)
void chunk_A(const float* __restrict__ qkv, const float* __restrict__ gg,
             float* __restrict__ h1out)
{
    __shared__ float sA[32][36];
    __shared__ unsigned short vTh[256][40];
    __shared__ unsigned short vTl[256][40];

    const int b    = blockIdx.x >> 5;
    const int c    = blockIdx.x & 31;
    const int tid  = threadIdx.x;
    const int lane = tid & 63;
    const int wv   = tid >> 6;
    const int l15  = lane & 15;
    const int kg   = lane >> 4;

    const size_t rb = (size_t)(b * S_ + c * CT);

    // ---- phase 1: A quadrant (qi,qj) per wave, K=512, bfx3 ----
    const int qi = wv >> 1, qj = wv & 1;
    {
        const float* qrow = qkv + (rb + qi * 16 + l15) * 1536;
        const float* krow = gg  + (rb + qj * 16 + l15) * 1536;
        f32x4 accA = (f32x4){0.f, 0.f, 0.f, 0.f};
#pragma unroll 4
        for (int ks = 0; ks < 16; ++ks) {
            const int kb = ks * 32 + kg * 8;
            bf16x8 ah, al, bh, bl;
            cvt8pair(qrow + kb, ah, al);
            cvt8pair(krow + kb, bh, bl);
            accA = __builtin_amdgcn_mfma_f32_16x16x32_bf16(ah, bh, accA, 0, 0, 0);
            accA = __builtin_amdgcn_mfma_f32_16x16x32_bf16(al, bh, accA, 0, 0, 0);
            accA = __builtin_amdgcn_mfma_f32_16x16x32_bf16(ah, bl, accA, 0, 0, 0);
        }
#pragma unroll
        for (int vi = 0; vi < 4; ++vi) {
            const int t = qi * 16 + kg * 4 + vi;
            const int s = qj * 16 + l15;
            sA[t][s] = (s <= t) ? accA[vi] : 0.f;
        }
    }

    // ---- phase 2: H1 = A V, per 256-e half (vT staged hi/lo) ----
    for (int half = 0; half < 2; ++half) {
        {
            const float* vp = qkv + rb * 1536 + 1024 + half * 256 + tid;
            unsigned int ph[16], pl[16];
#pragma unroll
            for (int u = 0; u < 32; u += 2) {
                float f0 = vp[(size_t)u * 1536];
                float f1 = vp[(size_t)(u + 1) * 1536];
                unsigned short h0 = f2bf(f0), h1 = f2bf(f1);
                unsigned short l0 = f2bf(f0 - bf2f(h0)), l1 = f2bf(f1 - bf2f(h1));
                ph[u >> 1] = (unsigned int)h0 | ((unsigned int)h1 << 16);
                pl[u >> 1] = (unsigned int)l0 | ((unsigned int)l1 << 16);
            }
            if (half == 1) __syncthreads();   // phase2_0 readers done
            uint4* dh = (uint4*)&vTh[tid][0];
            dh[0] = make_uint4(ph[0],  ph[1],  ph[2],  ph[3]);
            dh[1] = make_uint4(ph[4],  ph[5],  ph[6],  ph[7]);
            dh[2] = make_uint4(ph[8],  ph[9],  ph[10], ph[11]);
            dh[3] = make_uint4(ph[12], ph[13], ph[14], ph[15]);
            uint4* dl = (uint4*)&vTl[tid][0];
            dl[0] = make_uint4(pl[0],  pl[1],  pl[2],  pl[3]);
            dl[1] = make_uint4(pl[4],  pl[5],  pl[6],  pl[7]);
            dl[2] = make_uint4(pl[8],  pl[9],  pl[10], pl[11]);
            dl[3] = make_uint4(pl[12], pl[13], pl[14], pl[15]);
        }
        __syncthreads();   // sA (half 0) + vT ready

        bf16x8 afh[2], afl[2];
#pragma unroll
        for (int mf = 0; mf < 2; ++mf) {
            const float* ar = &sA[mf * 16 + l15][kg * 8];
#pragma unroll
            for (int j = 0; j < 8; ++j) {
                unsigned short h = f2bf(ar[j]);
                afh[mf][j] = (short)h;
                afl[mf][j] = (short)f2bf(ar[j] - bf2f(h));
            }
        }

        const int ebL = wv * 64;
        f32x4 acc[2][4];
#pragma unroll
        for (int mf = 0; mf < 2; ++mf)
#pragma unroll
            for (int nf = 0; nf < 4; ++nf) acc[mf][nf] = (f32x4){0.f, 0.f, 0.f, 0.f};

#pragma unroll
        for (int nf = 0; nf < 4; ++nf) {
            bf16x8 bh = *(const bf16x8*)&vTh[ebL + nf * 16 + l15][kg * 8];
            bf16x8 bl = *(const bf16x8*)&vTl[ebL + nf * 16 + l15][kg * 8];
#pragma unroll
            for (int mf = 0; mf < 2; ++mf) {
                acc[mf][nf] = __builtin_amdgcn_mfma_f32_16x16x32_bf16(afh[mf], bh, acc[mf][nf], 0, 0, 0);
                acc[mf][nf] = __builtin_amdgcn_mfma_f32_16x16x32_bf16(afl[mf], bh, acc[mf][nf], 0, 0, 0);
                acc[mf][nf] = __builtin_amdgcn_mfma_f32_16x16x32_bf16(afh[mf], bl, acc[mf][nf], 0, 0, 0);
            }
        }

#pragma unroll
        for (int mf = 0; mf < 2; ++mf)
#pragma unroll
            for (int vi = 0; vi < 4; ++vi) {
                const int t = mf * 16 + kg * 4 + vi;
                float* hrow = h1out + (rb + t) * 512 + half * 256 + ebL;
#pragma unroll
                for (int nf = 0; nf < 4; ++nf)
                    hrow[nf * 16 + l15] = acc[mf][nf][vi];
            }
    }
}

// ---------------------------------------------------------------------------
// chunk_cacc (unchanged): MFMA Cacc via LDS-transposed staging
// ---------------------------------------------------------------------------
__global__ __launch_bounds__(1024)
void chunk_cacc(const float* __restrict__ qkv, const float* __restrict__ gg,
                unsigned short* __restrict__ snap, int c0)
{
    __shared__ unsigned short vT[256][40];   // [e][u], padded pitch 40
    __shared__ unsigned short kT[512][40];   // [d][u]

    const int b    = blockIdx.x;
    const int lc   = blockIdx.y;
    const int eh   = blockIdx.z;
    const int c    = c0 + lc;
    const int tid  = threadIdx.x;
    const int lane = tid & 63;
    const int wv   = tid >> 6;          // 0..15
    const int l15  = lane & 15;
    const int kg   = lane >> 4;

    const size_t rb = (size_t)(b * S_ + c * CT);
    const size_t sb = ((size_t)lc * 8 + b) * 512;

    if (tid < 256) {
        const float* vp = qkv + rb * 1536 + 1024 + eh * 256 + tid;
        unsigned int pk[16];
#pragma unroll
        for (int u = 0; u < 32; u += 2) {
            float f0 = vp[(size_t)u * 1536];
            float f1 = vp[(size_t)(u + 1) * 1536];
            pk[u >> 1] = (unsigned int)f2bf(f0) | ((unsigned int)f2bf(f1) << 16);
        }
        uint4* dst = (uint4*)&vT[tid][0];
        dst[0] = make_uint4(pk[0],  pk[1],  pk[2],  pk[3]);
        dst[1] = make_uint4(pk[4],  pk[5],  pk[6],  pk[7]);
        dst[2] = make_uint4(pk[8],  pk[9],  pk[10], pk[11]);
        dst[3] = make_uint4(pk[12], pk[13], pk[14], pk[15]);
    } else if (tid < 768) {
        const int d = tid - 256;
        const float* kp = gg + rb * 1536 + d;
        unsigned int pk[16];
#pragma unroll
        for (int u = 0; u < 32; u += 2) {
            float f0 = kp[(size_t)u * 1536];
            float f1 = kp[(size_t)(u + 1) * 1536];
            pk[u >> 1] = (unsigned int)f2bf(f0) | ((unsigned int)f2bf(f1) << 16);
        }
        uint4* dst = (uint4*)&kT[d][0];
        dst[0] = make_uint4(pk[0],  pk[1],  pk[2],  pk[3]);
        dst[1] = make_uint4(pk[4],  pk[5],  pk[6],  pk[7]);
        dst[2] = make_uint4(pk[8],  pk[9],  pk[10], pk[11]);
        dst[3] = make_uint4(pk[12], pk[13], pk[14], pk[15]);
    }
    __syncthreads();

    const int ebase = (wv & 3) * 64;
    const int dbase = (wv >> 2) * 128;

    bf16x8 a[4];
#pragma unroll
    for (int me = 0; me < 4; ++me)
        a[me] = *(const bf16x8*)&vT[ebase + me * 16 + l15][kg * 8];

#pragma unroll
    for (int dp = 0; dp < 2; ++dp) {
        f32x4 acc[4][4];
#pragma unroll
        for (int me = 0; me < 4; ++me)
#pragma unroll
            for (int nd = 0; nd < 4; ++nd) acc[me][nd] = (f32x4){0.f, 0.f, 0.f, 0.f};

#pragma unroll
        for (int nd = 0; nd < 4; ++nd) {
            bf16x8 bfr = *(const bf16x8*)&kT[dbase + dp * 64 + nd * 16 + l15][kg * 8];
#pragma unroll
            for (int me = 0; me < 4; ++me)
                acc[me][nd] = __builtin_amdgcn_mfma_f32_16x16x32_bf16(a[me], bfr, acc[me][nd], 0, 0, 0);
        }

#pragma unroll
        for (int me = 0; me < 4; ++me)
#pragma unroll
            for (int vi = 0; vi < 4; ++vi) {
                const int e = eh * 256 + ebase + me * 16 + kg * 4 + vi;
                unsigned short* row = snap + (sb + e) * 512 + dbase + dp * 64;
#pragma unroll
                for (int nd = 0; nd < 4; ++nd)
                    row[nd * 16 + l15] = f2bf(acc[me][nd][vi]);
            }
    }
}

// ---------------------------------------------------------------------------
// chunk_cscan (unchanged): 32-step elementwise scan, snapshots in place
// ---------------------------------------------------------------------------
__global__ __launch_bounds__(256)
void chunk_cscan(const float* __restrict__ gg,
                 unsigned short* __restrict__ snap, float* __restrict__ Cst,
                 float* __restrict__ CfO, int c0, int nc)
{
    const int tid  = threadIdx.x;
    const int lane = tid & 63;
    const int wv   = tid >> 6;
    const int b    = blockIdx.x;
    const int eg   = blockIdx.y;
    const int dh   = blockIdx.z;
    const int ew   = eg * 16 + wv * 4;
    const int d0   = dh * 256 + 4 * lane;

    const float* gb = gg + (size_t)b * S_ * 1536;

    float C[4][4];
    if (c0 == 0) {
#pragma unroll
        for (int i = 0; i < 4; ++i)
#pragma unroll
            for (int j = 0; j < 4; ++j) C[i][j] = 0.f;
    } else {
#pragma unroll
        for (int j = 0; j < 4; ++j) {
            float4 cv = *(const float4*)&Cst[((size_t)b * 512 + d0 + j) * 512 + ew];
            C[0][j] = cv.x; C[1][j] = cv.y; C[2][j] = cv.z; C[3][j] = cv.w;
        }
    }

    ushort4 A0[4]; float4 F0;
    {
        const size_t sb = ((size_t)0 * 8 + b) * 512;
#pragma unroll
        for (int i = 0; i < 4; ++i)
            A0[i] = *(const ushort4*)(snap + (sb + ew + i) * 512 + d0);
        F0 = *(const float4*)(gb + (size_t)(c0 * CT) * 1536 + 512 + d0);
    }

    for (int lc = 0; lc < nc; ++lc) {
        ushort4 A1[4]; float4 F1;
        if (lc + 1 < nc) {
            const size_t sb = ((size_t)(lc + 1) * 8 + b) * 512;
#pragma unroll
            for (int i = 0; i < 4; ++i)
                A1[i] = *(const ushort4*)(snap + (sb + ew + i) * 512 + d0);
            F1 = *(const float4*)(gb + (size_t)((c0 + lc + 1) * CT) * 1536 + 512 + d0);
        }

        const int c = c0 + lc;
        if (c > 0) {
            const size_t sb = ((size_t)lc * 8 + b) * 512;
#pragma unroll
            for (int i = 0; i < 4; ++i) {
                uint2 pk;
                pk.x = (unsigned int)f2bf(C[i][0]) | ((unsigned int)f2bf(C[i][1]) << 16);
                pk.y = (unsigned int)f2bf(C[i][2]) | ((unsigned int)f2bf(C[i][3]) << 16);
                *(uint2*)(snap + (sb + ew + i) * 512 + d0) = pk;
            }
        }

        const float* fp = (const float*)&F0;
#pragma unroll
        for (int i = 0; i < 4; ++i) {
            C[i][0] = fp[0] * (C[i][0] + bf2f(A0[i].x));
            C[i][1] = fp[1] * (C[i][1] + bf2f(A0[i].y));
            C[i][2] = fp[2] * (C[i][2] + bf2f(A0[i].z));
            C[i][3] = fp[3] * (C[i][3] + bf2f(A0[i].w));
        }

        if (lc + 1 < nc) {
#pragma unroll
            for (int i = 0; i < 4; ++i) A0[i] = A1[i];
            F0 = F1;
        }
    }

    float* outp = (c0 + nc == NCT) ? CfO : Cst;
#pragma unroll
    for (int j = 0; j < 4; ++j)
        *(float4*)&outp[((size_t)b * 512 + d0 + j) * 512 + ew] =
            make_float4(C[0][j], C[1][j], C[2][j], C[3][j]);
}

// ---------------------------------------------------------------------------
// chunk_h2 (unchanged): H2 = Qt @ C0^T via mfma + fused combine epilogue
// ---------------------------------------------------------------------------
__global__ __launch_bounds__(256)
void chunk_h2(const float* __restrict__ qkv, const float* __restrict__ gg,
              const unsigned short* __restrict__ snap,
              const float* __restrict__ invd,
              float* __restrict__ hs, float* __restrict__ hlO, int c0)
{
    const int eh   = blockIdx.x;
    const int lc   = blockIdx.y;
    const int b    = blockIdx.z;
    const int c    = c0 + lc;
    const int tid  = threadIdx.x;
    const int lane = tid & 63;
    const int wv   = tid >> 6;
    const int n0   = eh * 256 + wv * 64;
    const int l15  = lane & 15;
    const int kg   = lane >> 4;

    const size_t rb = (size_t)(b * S_ + c * CT);

    f32x4 acc[2][4];
#pragma unroll
    for (int mf = 0; mf < 2; ++mf)
#pragma unroll
        for (int nf = 0; nf < 4; ++nf) acc[mf][nf] = (f32x4){0.f, 0.f, 0.f, 0.f};

    if (c > 0) {
        const unsigned short* cb = snap + ((size_t)(lc * 8 + b) * 512) * 512;
        const float* q0p = qkv + (rb + l15) * 1536;
        const float* q1p = qkv + (rb + 16 + l15) * 1536;
#pragma unroll 4
        for (int k0 = 0; k0 < 512; k0 += 32) {
            const int kb = k0 + kg * 8;
            bf16x8 a0 = cvt8(q0p + kb);
            bf16x8 a1 = cvt8(q1p + kb);
#pragma unroll
            for (int nf = 0; nf < 4; ++nf) {
                const unsigned short* bp = cb + (size_t)(n0 + nf * 16 + l15) * 512 + kb;
                bf16x8 bf = *(const bf16x8*)bp;
                acc[0][nf] = __builtin_amdgcn_mfma_f32_16x16x32_bf16(a0, bf, acc[0][nf], 0, 0, 0);
                acc[1][nf] = __builtin_amdgcn_mfma_f32_16x16x32_bf16(a1, bf, acc[1][nf], 0, 0, 0);
            }
        }
    }

    const float* ivp = invd + (size_t)b * S_ + c * CT;
#pragma unroll
    for (int mf = 0; mf < 2; ++mf) {
#pragma unroll
        for (int vi = 0; vi < 4; ++vi) {
            const int tl  = mf * 16 + kg * 4 + vi;
            const float ivt = ivp[tl];
            float* hrow       = hs + (rb + tl) * 512;
            const float* orow = gg + (rb + tl) * 1536 + 1024;
            const bool last = (c * CT + tl == S_ - 1);
#pragma unroll
            for (int nf = 0; nf < 4; ++nf) {
                const int e  = n0 + nf * 16 + l15;
                const float h1 = hrow[e];
                const float ov = orow[e];
                const float r  = (acc[mf][nf][vi] + h1) * ov * ivt;
                hrow[e] = r;
                if (last) hlO[(size_t)b * 512 + e] = r;
            }
        }
    }
}

// ---------------------------------------------------------------------------
extern "C" void kernel_launch(void* const* d_in, const int* in_sizes, int n_in,
                              void* d_out, int out_size, void* d_ws, size_t ws_size,
                              hipStream_t stream)
{
    const float* x    = (const float*)d_in[0];
    const float* W_in = (const float*)d_in[1];
    const float* b_in = (const float*)d_in[2];
    const float* W_ig = (const float*)d_in[3];
    const float* b_ig = (const float*)d_in[4];
    const float* W_fg = (const float*)d_in[5];
    const float* b_fg = (const float*)d_in[6];
    const float* W_og = (const float*)d_in[7];
    const float* b_og = (const float*)d_in[8];
    const float* W_out= (const float*)d_in[9];
    const float* b_out= (const float*)d_in[10];

    float* out   = (float*)d_out;                       // [8,1024,512]
    float* CfO   = out + (size_t)8 * 1024 * 512;        // [8,512,512]
    float* nfO   = CfO + (size_t)8 * 512 * 512;         // [8,512]
    float* hlO   = nfO + (size_t)8 * 512;               // [8,512]

    float* qkv = (float*)d_ws;                          // [8192,1536]
    float* gg  = qkv + (size_t)8192 * 1536;             // [8192,1536]
    float* hsb = gg  + (size_t)8192 * 1536;             // [8192,512]
    double* nend = (double*)hsb;                        // overlay (dead later)
    double* Dend = nend + (size_t)8 * NDCH * 512;
    double* n0a  = Dend + (size_t)8 * NDCH * 512;
    float*  invd = hsb + (size_t)8192 * 512;            // [8,1024]
    float*  Cst  = invd + 8192;                         // [8,512,512] f32
    unsigned short* Wh = (unsigned short*)(Cst + (size_t)8 * 512 * 512); // [3584][512]
    unsigned short* Wl = Wh + (size_t)3584 * 512;
    unsigned short* snap = Wl + (size_t)3584 * 512;

    const size_t WSB   = (size_t)((char*)snap - (char*)d_ws);   // bytes thru Wt
    const size_t SNAPC = (size_t)8 * 512 * 512 * 2;             // 4 MB / slot
    const size_t SLOTS = (size_t)8 * 512 * 512;                 // shorts / slot
    int nc; unsigned short* Ah;
    if (ws_size >= WSB + 32 * SNAPC)      { nc = 32; Ah = snap; }
    else if (ws_size >= WSB + 8 * SNAPC)  { nc = 8;  Ah = snap; }
    else                                  { nc = 2;  Ah = snap + 2 * (SNAPC / 2); }
    unsigned short* Al = Ah + (size_t)8192 * 512;

    // fused v-split destination (snap slots 4..7; safe while slots unused)
    unsigned short* Av  = nullptr;
    unsigned short* Alv = nullptr;
    if (nc >= 8) { Av = snap + 4 * SLOTS; Alv = Av + (size_t)8192 * 512; }

    // 0. weights -> bf16 hi/lo, tiled-swizzled [n][k] layout (persistent)
    prep_w<<<dim3(14, 16), 256, 0, stream>>>(W_in, W_ig, W_fg, W_og, W_out, Wh, Wl);
    // 1. proj + tanh(q,k):  qkv = act(x @ W_in[:, :1536]); fused v bf16 split
    cvt_a<<<dim3(32, 16), 256, 0, stream>>>(x, 512, Ah, Al);
    gemm_mfma<0><<<768, 256, 0, stream>>>(
        Ah, Al, Wh, Wl, qkv, b_in, b_in, b_in, qkv, 1536, Av, Alv);
    // 2. gates: gg = [i*k | f | o]
    const unsigned short* Aga = Av  ? Av  : Ah;
    const unsigned short* Agl = Alv ? Alv : Al;
    if (!Av) cvt_a<<<dim3(32, 16), 256, 0, stream>>>(qkv + 1024, 1536, Ah, Al);
    gemm_mfma<1><<<768, 256, 0, stream>>>(
        Aga, Agl, Wh, Wl, qkv, b_ig, b_fg, b_og, gg, 1536, nullptr, nullptr);
    // 3. f64 denominators on ORIGINAL q/ik/f
    nscan_local <<<1024, 512, 0, stream>>>(gg, nend, Dend);
    nscan_stitch<<<   8, 512, 0, stream>>>(nend, Dend, n0a, nfO);
    denom_kernel<<< 256, 256, 0, stream>>>(qkv, gg, n0a, invd);
    // 4. chunk transforms + intra-chunk H1 (MFMA)
    chunk_prep<<<256, 512, 0, stream>>>(qkv, gg);
    chunk_A<<<256, 256, 0, stream>>>(qkv, gg, hsb);
    // 5. chunk recurrence (Acvt/Av in snap region dead from here on)
    for (int c0 = 0; c0 < NCT; c0 += nc) {
        chunk_cacc <<<dim3(8, nc, 2), 1024, 0, stream>>>(qkv, gg, snap, c0);
        chunk_cscan<<<dim3(8, 32, 2), 256, 0, stream>>>(gg, snap, Cst, CfO, c0, nc);
        chunk_h2   <<<dim3(2, nc, 8), 256, 0, stream>>>(qkv, gg, snap, invd, hsb, hlO, c0);
    }
    // 6. out = hs @ W_out + b_out   (snap dead -> Acvt reuse safe)
    cvt_a<<<dim3(32, 16), 256, 0, stream>>>(hsb, 512, Ah, Al);
    gemm_mfma<2><<<256, 256, 0, stream>>>(
        Ah, Al, Wh, Wl, qkv, b_out, b_out, b_out, out, 512, nullptr, nullptr);
}